// Round 3
// baseline (463.895 us; speedup 1.0000x reference)
//
#include <hip/hip_runtime.h>
#include <hip/hip_bf16.h>

// ---------------------------------------------------------------------------
// TokenDiscrepancyLoss: loss = 0.1 * sum_{mask} [ (||t||^2 + sum_c p_c (||c||^2 - 2 t.c)) / H ]
// with p = softmax(hs @ W + b) over C=8192.
//
// R3: split the dual GEMM into two m97-shaped single GEMMs (32 KiB LDS,
// 64-AGPR acc, 3 blocks/CU) with ct = csq - 2*cross - 1024 materialized as
// bf16 ctT[col][row] between them. Host-side fallback to the R2 fused kernel
// if ws_size can't hold ctT (deterministic -> graph-capture safe).
// ---------------------------------------------------------------------------

#define H        1024
#define CBN      8192
#define NTOK     8192
#define MT       128              // token rows per tile
#define NTILE    128              // codeword cols per tile
#define BK       64               // K chunk
#define NKC      (H / BK)         // 16
#define NCHK     (CBN / 64)       // 128 partial strips (one per 64-col wave tile)
#define LOSSW    0.1f
#define CTC      1024.0f          // centering constant for bf16 ct storage

typedef __attribute__((ext_vector_type(4))) float  f32x4;
typedef __attribute__((ext_vector_type(8))) short  s16x8;   // 8 bf16 (4 VGPRs)

__device__ __forceinline__ unsigned short f2bf(float f) {
  union { float f; unsigned u; } x; x.f = f;
  return (unsigned short)((x.u + 0x7FFFu + ((x.u >> 16) & 1u)) >> 16); // RNE
}
__device__ __forceinline__ float bf2f(unsigned short u) {
  union { unsigned u; float f; } x; x.u = (unsigned)u << 16;
  return x.f;
}
__device__ __forceinline__ f32x4 mfma16(s16x8 a, s16x8 b, f32x4 c) {
  return __builtin_amdgcn_mfma_f32_16x16x32_bf16(a, b, c, 0, 0, 0);
}
// async global->LDS DMA, 16B/lane; LDS dest = wave-uniform base + lane*16
__device__ __forceinline__ void load_lds16(const void* g, void* l) {
  __builtin_amdgcn_global_load_lds((const __attribute__((address_space(1))) void*)g,
                                   (__attribute__((address_space(3))) void*)l,
                                   16, 0, 0);
}

// --------------------------- compact active tokens -------------------------
__global__ __launch_bounds__(256) void k_compact(const int* __restrict__ ids,
                                                 int* __restrict__ list,
                                                 int* __restrict__ counter) {
  int t = threadIdx.x;
  int f = 0;
  #pragma unroll
  for (int j = 0; j < 16; ++j) f |= ids[2 * (t * 16 + j) + 1];
  int anyodd = __syncthreads_or(f);

  int i = blockIdx.x * 256 + t;
  int v = anyodd ? ids[i] : ids[2 * i];
  bool act = (v == 1);
  unsigned long long mask = __ballot(act);
  int lane = t & 63;
  int base = 0;
  if (lane == 0) base = atomicAdd(counter, __popcll(mask));
  base = __shfl(base, 0);
  if (act) {
    int off = __popcll(mask & ((1ull << lane) - 1ull));
    list[base + off] = i;
  }
}

// ------------------- codebook -> bf16 + per-codeword ||c||^2 ---------------
__global__ __launch_bounds__(256) void k_prep_cb(const float* __restrict__ cb,
                                                 unsigned short* __restrict__ cbb,
                                                 float* __restrict__ csq) {
  int c = blockIdx.x * 4 + (threadIdx.x >> 6);
  int lane = threadIdx.x & 63;
  const float4* src = (const float4*)(cb + (size_t)c * H);
  float ss = 0.f;
  #pragma unroll
  for (int i = 0; i < 4; ++i) {
    float4 v = src[lane + 64 * i];
    ss += v.x * v.x + v.y * v.y + v.z * v.z + v.w * v.w;
    ushort4 p;
    p.x = f2bf(v.x); p.y = f2bf(v.y); p.z = f2bf(v.z); p.w = f2bf(v.w);
    *(ushort4*)(cbb + (size_t)c * H + (size_t)(lane + 64 * i) * 4) = p;
  }
  #pragma unroll
  for (int d = 1; d < 64; d <<= 1) ss += __shfl_xor(ss, d);
  if (lane == 0) csq[c] = ss;
}

// --------------------- W [H,C] fp32 -> W^T [C,H] bf16 ----------------------
__global__ __launch_bounds__(256) void k_prep_w(const float* __restrict__ W,
                                                unsigned short* __restrict__ Wtb) {
  __shared__ float tile[64][68];
  int c0 = blockIdx.x * 64, k0 = blockIdx.y * 64;
  int r = threadIdx.x >> 2, q = threadIdx.x & 3;
  const float4* src = (const float4*)(W + (size_t)(k0 + r) * CBN + c0);
  #pragma unroll
  for (int i = 0; i < 4; ++i) {
    float4 v = src[q * 4 + i];
    *(float4*)&tile[r][q * 16 + i * 4] = v;
  }
  __syncthreads();
  unsigned short* dst = Wtb + (size_t)(c0 + r) * H + k0;
  #pragma unroll
  for (int i = 0; i < 4; ++i) {
    ushort4 p;
    p.x = f2bf(tile[q * 16 + i * 4 + 0][r]);
    p.y = f2bf(tile[q * 16 + i * 4 + 1][r]);
    p.z = f2bf(tile[q * 16 + i * 4 + 2][r]);
    p.w = f2bf(tile[q * 16 + i * 4 + 3][r]);
    *(ushort4*)(dst + q * 16 + i * 4) = p;
  }
}

// --------- gather active tokens -> bf16 rows + exact fp32 ||t||^2 ----------
__global__ __launch_bounds__(256) void k_prep_a(
    const float* __restrict__ hs, const float* __restrict__ tg,
    const int* __restrict__ list, const int* __restrict__ counter,
    unsigned short* __restrict__ Ahs, unsigned short* __restrict__ Atg,
    float* __restrict__ tsq) {
  const int n = *counter;
  const int n_pad = (n + MT - 1) & ~(MT - 1);
  const int ga = blockIdx.x * 4 + (threadIdx.x >> 6);
  if (ga >= n_pad) return;
  const int lane = threadIdx.x & 63;
  const int tok = list[(ga < n) ? ga : 0];
  const float4* h4 = (const float4*)(hs + (size_t)tok * H);
  const float4* t4 = (const float4*)(tg + (size_t)tok * H);
  unsigned short* ah = Ahs + (size_t)ga * H;
  unsigned short* at = Atg + (size_t)ga * H;
  float ss = 0.f;
  #pragma unroll
  for (int i = 0; i < 4; ++i) {
    float4 v = h4[lane + 64 * i];
    ushort4 p;
    p.x = f2bf(v.x); p.y = f2bf(v.y); p.z = f2bf(v.z); p.w = f2bf(v.w);
    *(ushort4*)(ah + (size_t)(lane + 64 * i) * 4) = p;
    float4 u = t4[lane + 64 * i];
    ss += u.x * u.x + u.y * u.y + u.z * u.z + u.w * u.w;
    ushort4 q;
    q.x = f2bf(u.x); q.y = f2bf(u.y); q.z = f2bf(u.z); q.w = f2bf(u.w);
    *(ushort4*)(at + (size_t)(lane + 64 * i) * 4) = q;
  }
  #pragma unroll
  for (int d = 1; d < 64; d <<= 1) ss += __shfl_xor(ss, d);
  if (lane == 0) tsq[ga] = ss;
}

// ---------------- split kernel 1: cross GEMM -> bf16 ctT -------------------
// grid (64,64), block 256 = 4 waves 2x2; wave tile 64x64; m97 resource shape.
__global__ __launch_bounds__(256, 3) void k_cross(
    const unsigned short* __restrict__ Atg, const unsigned short* __restrict__ Cbb,
    const float* __restrict__ csq, const int* __restrict__ counter,
    unsigned short* __restrict__ ctT) {
  const int n = *counter;
  const int tilex = blockIdx.x;
  if (tilex * MT >= n) return;
  const int tiley = blockIdx.y;

  __shared__ __align__(16) unsigned short sA[MT * BK];
  __shared__ __align__(16) unsigned short sB[NTILE * BK];

  const int tid  = threadIdx.x;
  const int w    = tid >> 6, lane = tid & 63;
  const int wr   = w >> 1,   wc   = w & 1;
  const int quad = lane >> 4, lcol = lane & 15;
  const int swz  = lcol & 7;
  const int rsub = lane >> 3;
  const int cg   = (lane & 7) ^ rsub;
  const size_t rowA0H = (size_t)tilex * MT * H;
  const size_t colB0H = (size_t)tiley * NTILE * H;

  f32x4 acc[4][4];
  #pragma unroll
  for (int mb = 0; mb < 4; ++mb)
    #pragma unroll
    for (int nb = 0; nb < 4; ++nb) acc[mb][nb] = (f32x4){0.f, 0.f, 0.f, 0.f};

  for (int kc = 0; kc < NKC; ++kc) {
    #pragma unroll
    for (int i = 0; i < 4; ++i) {
      const int li  = w + 4 * i;
      const int rit = li * 8 + rsub;
      const size_t goff = (size_t)rit * H + (size_t)(kc * BK + cg * 8);
      load_lds16(Atg + rowA0H + goff, &sA[li * 512]);
      load_lds16(Cbb + colB0H + goff, &sB[li * 512]);
    }
    __syncthreads();
    #pragma unroll
    for (int ks = 0; ks < 2; ++ks) {
      const int cA = (((ks * 4 + quad) ^ swz) * 8);
      s16x8 af[4], bf[4];
      #pragma unroll
      for (int mb = 0; mb < 4; ++mb)
        af[mb] = *(const s16x8*)&sA[(wr * 64 + mb * 16 + lcol) * BK + cA];
      #pragma unroll
      for (int nb = 0; nb < 4; ++nb)
        bf[nb] = *(const s16x8*)&sB[(wc * 64 + nb * 16 + lcol) * BK + cA];
      #pragma unroll
      for (int mb = 0; mb < 4; ++mb)
        #pragma unroll
        for (int nb = 0; nb < 4; ++nb)
          acc[mb][nb] = mfma16(af[mb], bf[nb], acc[mb][nb]);
    }
    __syncthreads();
  }

  // epilogue: ct = csq - 2*cross - CTC, bf16, stored transposed ctT[col][row]
  #pragma unroll
  for (int nb = 0; nb < 4; ++nb) {
    const int col = tiley * NTILE + wc * 64 + nb * 16 + lcol;
    const float cqc = csq[col] - CTC;
    unsigned short* cbase = ctT + (size_t)col * NTOK + tilex * MT + wr * 64;
    #pragma unroll
    for (int mb = 0; mb < 4; ++mb) {
      ushort4 st;
      st.x = f2bf(cqc - 2.f * acc[mb][nb][0]);
      st.y = f2bf(cqc - 2.f * acc[mb][nb][1]);
      st.z = f2bf(cqc - 2.f * acc[mb][nb][2]);
      st.w = f2bf(cqc - 2.f * acc[mb][nb][3]);
      *(ushort4*)(cbase + mb * 16 + quad * 4) = st;
    }
  }
}

// -------- split kernel 2: logits GEMM + softmax partials (reads ctT) -------
__global__ __launch_bounds__(256, 3) void k_logit(
    const unsigned short* __restrict__ Ahs, const unsigned short* __restrict__ Wtb,
    const float* __restrict__ bias, const unsigned short* __restrict__ ctT,
    const int* __restrict__ counter,
    float* __restrict__ pm, float* __restrict__ pl, float* __restrict__ ps) {
  const int n = *counter;
  const int tilex = blockIdx.x;
  if (tilex * MT >= n) return;
  const int tiley = blockIdx.y;

  __shared__ __align__(16) unsigned short sA[MT * BK];
  __shared__ __align__(16) unsigned short sB[NTILE * BK];

  const int tid  = threadIdx.x;
  const int w    = tid >> 6, lane = tid & 63;
  const int wr   = w >> 1,   wc   = w & 1;
  const int quad = lane >> 4, lcol = lane & 15;
  const int swz  = lcol & 7;
  const int rsub = lane >> 3;
  const int cg   = (lane & 7) ^ rsub;
  const size_t rowA0H = (size_t)tilex * MT * H;
  const size_t colB0H = (size_t)tiley * NTILE * H;

  f32x4 acc[4][4];
  #pragma unroll
  for (int mb = 0; mb < 4; ++mb)
    #pragma unroll
    for (int nb = 0; nb < 4; ++nb) acc[mb][nb] = (f32x4){0.f, 0.f, 0.f, 0.f};

  for (int kc = 0; kc < NKC; ++kc) {
    #pragma unroll
    for (int i = 0; i < 4; ++i) {
      const int li  = w + 4 * i;
      const int rit = li * 8 + rsub;
      const size_t goff = (size_t)rit * H + (size_t)(kc * BK + cg * 8);
      load_lds16(Ahs + rowA0H + goff, &sA[li * 512]);
      load_lds16(Wtb + colB0H + goff, &sB[li * 512]);
    }
    __syncthreads();
    #pragma unroll
    for (int ks = 0; ks < 2; ++ks) {
      const int cA = (((ks * 4 + quad) ^ swz) * 8);
      s16x8 af[4], bf[4];
      #pragma unroll
      for (int mb = 0; mb < 4; ++mb)
        af[mb] = *(const s16x8*)&sA[(wr * 64 + mb * 16 + lcol) * BK + cA];
      #pragma unroll
      for (int nb = 0; nb < 4; ++nb)
        bf[nb] = *(const s16x8*)&sB[(wc * 64 + nb * 16 + lcol) * BK + cA];
      #pragma unroll
      for (int mb = 0; mb < 4; ++mb)
        #pragma unroll
        for (int nb = 0; nb < 4; ++nb)
          acc[mb][nb] = mfma16(af[mb], bf[nb], acc[mb][nb]);
    }
    __syncthreads();
  }

  // epilogue: logits + ct readback -> (m, l, s-centered) per 64-col strip
  float bv[4];
  const unsigned short* cbase[4];
  #pragma unroll
  for (int nb = 0; nb < 4; ++nb) {
    const int col = tiley * NTILE + wc * 64 + nb * 16 + lcol;
    bv[nb] = bias[col];
    cbase[nb] = ctT + (size_t)col * NTOK + tilex * MT + wr * 64;
  }
  const int chunk = tiley * 2 + wc;
  #pragma unroll
  for (int mb = 0; mb < 4; ++mb) {
    ushort4 c4[4];
    #pragma unroll
    for (int nb = 0; nb < 4; ++nb)
      c4[nb] = *(const ushort4*)(cbase[nb] + mb * 16 + quad * 4);
    const unsigned short* cc = (const unsigned short*)&c4[0];
    #pragma unroll
    for (int j = 0; j < 4; ++j) {
      float lg[4], ct[4];
      #pragma unroll
      for (int nb = 0; nb < 4; ++nb) {
        lg[nb] = acc[mb][nb][j] + bv[nb];
        ct[nb] = bf2f(cc[nb * 4 + j]);
      }
      float tmax = fmaxf(fmaxf(lg[0], lg[1]), fmaxf(lg[2], lg[3]));
      #pragma unroll
      for (int d = 1; d < 16; d <<= 1) tmax = fmaxf(tmax, __shfl_xor(tmax, d));
      float le = 0.f, se = 0.f;
      #pragma unroll
      for (int nb = 0; nb < 4; ++nb) {
        const float e = __expf(lg[nb] - tmax);
        le += e; se += e * ct[nb];
      }
      #pragma unroll
      for (int d = 1; d < 16; d <<= 1) {
        le += __shfl_xor(le, d);
        se += __shfl_xor(se, d);
      }
      if (lcol == 0) {
        const int row = tilex * MT + wr * 64 + mb * 16 + quad * 4 + j;
        pm[chunk * NTOK + row] = tmax;
        pl[chunk * NTOK + row] = le;
        ps[chunk * NTOK + row] = se;
      }
    }
  }
}

// ---------------- R2 fused dual-GEMM (ws-size fallback path) ---------------
__global__ __launch_bounds__(256, 2) void k_fused(
    const unsigned short* __restrict__ Ahs, const unsigned short* __restrict__ Atg,
    const unsigned short* __restrict__ Wtb, const unsigned short* __restrict__ Cbb,
    const float* __restrict__ bias, const float* __restrict__ csq,
    const int* __restrict__ counter,
    float* __restrict__ pm, float* __restrict__ pl, float* __restrict__ ps) {
  const int n = *counter;
  const int tilex = blockIdx.x;
  if (tilex * MT >= n) return;
  const int tiley = blockIdx.y;

  __shared__ __align__(16) unsigned short sA1[MT * BK];
  __shared__ __align__(16) unsigned short sA2[MT * BK];
  __shared__ __align__(16) unsigned short sB1[NTILE * BK];
  __shared__ __align__(16) unsigned short sB2[NTILE * BK];

  const int tid  = threadIdx.x;
  const int w    = tid >> 6, lane = tid & 63;
  const int wr   = w >> 1,   wc   = w & 1;
  const int quad = lane >> 4, lcol = lane & 15;
  const int swz  = lcol & 7;
  const int rsub = lane >> 3;
  const int cg   = (lane & 7) ^ rsub;
  const size_t rowA0H = (size_t)tilex * MT * H;
  const size_t colB0H = (size_t)tiley * NTILE * H;

  f32x4 acc1[4][4], acc2[4][4];
  #pragma unroll
  for (int mb = 0; mb < 4; ++mb)
    #pragma unroll
    for (int nb = 0; nb < 4; ++nb) {
      acc1[mb][nb] = (f32x4){0.f, 0.f, 0.f, 0.f};
      acc2[mb][nb] = (f32x4){0.f, 0.f, 0.f, 0.f};
    }

  for (int kc = 0; kc < NKC; ++kc) {
    #pragma unroll
    for (int i = 0; i < 4; ++i) {
      const int li  = w + 4 * i;
      const int rit = li * 8 + rsub;
      const size_t goff = (size_t)rit * H + (size_t)(kc * BK + cg * 8);
      load_lds16(Ahs + rowA0H + goff, &sA1[li * 512]);
      load_lds16(Atg + rowA0H + goff, &sA2[li * 512]);
      load_lds16(Wtb + colB0H + goff, &sB1[li * 512]);
      load_lds16(Cbb + colB0H + goff, &sB2[li * 512]);
    }
    __syncthreads();
    #pragma unroll
    for (int ks = 0; ks < 2; ++ks) {
      const int cA = (((ks * 4 + quad) ^ swz) * 8);
      {
        s16x8 af[4], bf[4];
        #pragma unroll
        for (int mb = 0; mb < 4; ++mb)
          af[mb] = *(const s16x8*)&sA1[(wr * 64 + mb * 16 + lcol) * BK + cA];
        #pragma unroll
        for (int nb = 0; nb < 4; ++nb)
          bf[nb] = *(const s16x8*)&sB1[(wc * 64 + nb * 16 + lcol) * BK + cA];
        #pragma unroll
        for (int mb = 0; mb < 4; ++mb)
          #pragma unroll
          for (int nb = 0; nb < 4; ++nb)
            acc1[mb][nb] = mfma16(af[mb], bf[nb], acc1[mb][nb]);
      }
      {
        s16x8 af[4], bf[4];
        #pragma unroll
        for (int mb = 0; mb < 4; ++mb)
          af[mb] = *(const s16x8*)&sA2[(wr * 64 + mb * 16 + lcol) * BK + cA];
        #pragma unroll
        for (int nb = 0; nb < 4; ++nb)
          bf[nb] = *(const s16x8*)&sB2[(wc * 64 + nb * 16 + lcol) * BK + cA];
        #pragma unroll
        for (int mb = 0; mb < 4; ++mb)
          #pragma unroll
          for (int nb = 0; nb < 4; ++nb)
            acc2[mb][nb] = mfma16(af[mb], bf[nb], acc2[mb][nb]);
      }
    }
    __syncthreads();
  }

  float bv[4], cq[4];
  #pragma unroll
  for (int nb = 0; nb < 4; ++nb) {
    const int col = tiley * NTILE + wc * 64 + nb * 16 + lcol;
    bv[nb] = bias[col];
    cq[nb] = csq[col];
  }
  const int chunk = tiley * 2 + wc;
  #pragma unroll
  for (int mb = 0; mb < 4; ++mb) {
    #pragma unroll
    for (int j = 0; j < 4; ++j) {
      float lg[4], ct[4];
      #pragma unroll
      for (int nb = 0; nb < 4; ++nb) {
        lg[nb] = acc1[mb][nb][j] + bv[nb];
        ct[nb] = cq[nb] - 2.f * acc2[mb][nb][j];
      }
      float tmax = fmaxf(fmaxf(lg[0], lg[1]), fmaxf(lg[2], lg[3]));
      #pragma unroll
      for (int d = 1; d < 16; d <<= 1) tmax = fmaxf(tmax, __shfl_xor(tmax, d));
      float le = 0.f, se = 0.f;
      #pragma unroll
      for (int nb = 0; nb < 4; ++nb) {
        const float e = __expf(lg[nb] - tmax);
        le += e; se += e * ct[nb];
      }
      #pragma unroll
      for (int d = 1; d < 16; d <<= 1) {
        le += __shfl_xor(le, d);
        se += __shfl_xor(se, d);
      }
      if (lcol == 0) {
        const int row = tilex * MT + wr * 64 + mb * 16 + quad * 4 + j;
        pm[chunk * NTOK + row] = tmax;
        pl[chunk * NTOK + row] = le;
        ps[chunk * NTOK + row] = se;
      }
    }
  }
}

// ----------------- merge strip partials -> scalar loss ---------------------
__global__ __launch_bounds__(256) void k_merge(
    const int* __restrict__ counter, const float* __restrict__ tsq,
    const float* __restrict__ pm, const float* __restrict__ pl,
    const float* __restrict__ ps, float* __restrict__ out, float addc) {
  const int n = *counter;
  const int ga = blockIdx.x * 256 + threadIdx.x;
  float val = 0.f;
  if (ga < n) {
    float M = -1e30f;
    for (int j = 0; j < NCHK; ++j) M = fmaxf(M, pm[j * NTOK + ga]);
    float L = 0.f, S = 0.f;
    for (int j = 0; j < NCHK; ++j) {
      const float e = __expf(pm[j * NTOK + ga] - M);
      L += pl[j * NTOK + ga] * e;
      S += ps[j * NTOK + ga] * e;
    }
    val = (tsq[ga] + addc + S / L) * (LOSSW / (float)H);
  }
  #pragma unroll
  for (int d = 1; d < 64; d <<= 1) val += __shfl_xor(val, d);
  __shared__ float wsum[4];
  if ((threadIdx.x & 63) == 0) wsum[threadIdx.x >> 6] = val;
  __syncthreads();
  if (threadIdx.x == 0)
    atomicAdd(out, wsum[0] + wsum[1] + wsum[2] + wsum[3]);
}

// ---------------------------------------------------------------------------
extern "C" void kernel_launch(void* const* d_in, const int* in_sizes, int n_in,
                              void* d_out, int out_size, void* d_ws, size_t ws_size,
                              hipStream_t stream) {
  const float* hs   = (const float*)d_in[0];
  const int*   ids  = (const int*)d_in[1];
  const float* tg   = (const float*)d_in[2];
  const float* cb   = (const float*)d_in[3];
  const float* W    = (const float*)d_in[4];
  const float* bias = (const float*)d_in[5];

  char* ws = (char*)d_ws;
  constexpr size_t OFF_CNT  = 0;
  constexpr size_t OFF_WTB  = 256;
  constexpr size_t OFF_CBB  = OFF_WTB  + (size_t)CBN * H * 2;
  constexpr size_t OFF_AHS  = OFF_CBB  + (size_t)CBN * H * 2;
  constexpr size_t OFF_ATG  = OFF_AHS  + (size_t)NTOK * H * 2;
  constexpr size_t OFF_CSQ  = OFF_ATG  + (size_t)NTOK * H * 2;
  constexpr size_t OFF_TSQ  = OFF_CSQ  + (size_t)CBN * 4;
  constexpr size_t OFF_LIST = OFF_TSQ  + (size_t)NTOK * 4;
  constexpr size_t OFF_PM   = OFF_LIST + (size_t)NTOK * 4;
  constexpr size_t OFF_PL   = OFF_PM   + (size_t)NCHK * NTOK * 4;
  constexpr size_t OFF_PS   = OFF_PL   + (size_t)NCHK * NTOK * 4;
  constexpr size_t OFF_CTT  = OFF_PS   + (size_t)NCHK * NTOK * 4;
  constexpr size_t REQ_SPLIT = OFF_CTT + (size_t)CBN * NTOK * 2;   // ~204 MiB

  int*            counter = (int*)(ws + OFF_CNT);
  unsigned short* Wtb     = (unsigned short*)(ws + OFF_WTB);
  unsigned short* Cbb     = (unsigned short*)(ws + OFF_CBB);
  unsigned short* Ahs     = (unsigned short*)(ws + OFF_AHS);
  unsigned short* Atg     = (unsigned short*)(ws + OFF_ATG);
  float*          csq     = (float*)(ws + OFF_CSQ);
  float*          tsq     = (float*)(ws + OFF_TSQ);
  int*            list    = (int*)(ws + OFF_LIST);
  float*          pm      = (float*)(ws + OFF_PM);
  float*          pl      = (float*)(ws + OFF_PL);
  float*          ps      = (float*)(ws + OFF_PS);
  unsigned short* ctT     = (unsigned short*)(ws + OFF_CTT);

  hipMemsetAsync(counter, 0, sizeof(int), stream);
  hipMemsetAsync(d_out, 0, sizeof(float), stream);

  k_compact<<<NTOK / 256, 256, 0, stream>>>(ids, list, counter);
  k_prep_cb<<<CBN / 4, 256, 0, stream>>>(cb, Cbb, csq);
  k_prep_w<<<dim3(CBN / 64, H / 64), 256, 0, stream>>>(W, Wtb);
  k_prep_a<<<NTOK / 4, 256, 0, stream>>>(hs, tg, list, counter, Ahs, Atg, tsq);

  if (ws_size >= REQ_SPLIT) {
    k_cross<<<dim3(NTOK / MT, CBN / NTILE), 256, 0, stream>>>(
        Atg, Cbb, csq, counter, ctT);
    k_logit<<<dim3(NTOK / MT, CBN / NTILE), 256, 0, stream>>>(
        Ahs, Wtb, bias, ctT, counter, pm, pl, ps);
    k_merge<<<NTOK / 256, 256, 0, stream>>>(counter, tsq, pm, pl, ps,
                                            (float*)d_out, CTC);
  } else {
    k_fused<<<dim3(NTOK / MT, CBN / NTILE), 256, 0, stream>>>(
        Ahs, Atg, Wtb, Cbb, bias, csq, counter, pm, pl, ps);
    k_merge<<<NTOK / 256, 256, 0, stream>>>(counter, tsq, pm, pl, ps,
                                            (float*)d_out, 0.0f);
  }
}

// Round 4
// 384.540 us; speedup vs baseline: 1.2064x; 1.2064x over previous
//
#include <hip/hip_runtime.h>
#include <hip/hip_bf16.h>

// ---------------------------------------------------------------------------
// TokenDiscrepancyLoss: loss = 0.1 * sum_{mask} [ (||t||^2 + sum_c p_c (||c||^2 - 2 t.c)) / H ]
// with p = softmax(hs @ W + b) over C=8192.
//
// R4: split GEMMs get an AITER-style software pipeline: double-buffered LDS,
// raw s_barrier + s_waitcnt vmcnt(8) (never a full drain while prefetch is in
// flight). ct intermediate stored as per-(block,wave)-blobs -> fully coalesced
// store/readback. XCD-aware tile swizzle for B-panel L2 residency.
// ---------------------------------------------------------------------------

#define H        1024
#define CBN      8192
#define NTOK     8192
#define MT       128              // token rows per tile
#define NTILE    128              // codeword cols per tile
#define BK       64               // K chunk
#define NKC      (H / BK)         // 16
#define NCHK     (CBN / 64)       // 128 partial strips (one per 64-col wave tile)
#define LOSSW    0.1f
#define CTC      1024.0f          // centering constant for bf16 ct storage

typedef __attribute__((ext_vector_type(4))) float  f32x4;
typedef __attribute__((ext_vector_type(8))) short  s16x8;   // 8 bf16 (4 VGPRs)
typedef __attribute__((ext_vector_type(8))) unsigned short u16x8;

__device__ __forceinline__ unsigned short f2bf(float f) {
  union { float f; unsigned u; } x; x.f = f;
  return (unsigned short)((x.u + 0x7FFFu + ((x.u >> 16) & 1u)) >> 16); // RNE
}
__device__ __forceinline__ float bf2f(unsigned short u) {
  union { unsigned u; float f; } x; x.u = (unsigned)u << 16;
  return x.f;
}
__device__ __forceinline__ f32x4 mfma16(s16x8 a, s16x8 b, f32x4 c) {
  return __builtin_amdgcn_mfma_f32_16x16x32_bf16(a, b, c, 0, 0, 0);
}
// async global->LDS DMA, 16B/lane; LDS dest = wave-uniform base + lane*16
__device__ __forceinline__ void load_lds16(const void* g, void* l) {
  __builtin_amdgcn_global_load_lds((const __attribute__((address_space(1))) void*)g,
                                   (__attribute__((address_space(3))) void*)l,
                                   16, 0, 0);
}
// fine-grained pipeline primitives (m139 pattern). vmcnt retires in order, so
// vmcnt(8) == "my previous DMA batch of 8 has fully landed in LDS"; stray
// loads scheduled in-between only make the wait conservative, never unsafe.
__device__ __forceinline__ void wait_vm8() { asm volatile("s_waitcnt vmcnt(8)" ::: "memory"); }
__device__ __forceinline__ void wait_vm0() { asm volatile("s_waitcnt vmcnt(0)" ::: "memory"); }
__device__ __forceinline__ void barrier_raw() { asm volatile("s_barrier" ::: "memory"); }

// XCD-aware tile mapping: hardware round-robins consecutive workgroups over
// the 8 XCDs, so flat%8 clusters; give each XCD a contiguous 8-wide tiley
// band (2 MB of B panels resident per XCD L2). Pure perf heuristic; both
// GEMM kernels use the identical mapping so the ct blobs line up.
__device__ __forceinline__ void tile_map(int* tilex, int* tiley) {
  const int flat = blockIdx.y * 64 + blockIdx.x;
  const int xcd = flat & 7, loc = flat >> 3;
  *tiley = xcd * 8 + (loc & 7);
  *tilex = loc >> 3;
}

// --------------------------- compact active tokens -------------------------
__global__ __launch_bounds__(256) void k_compact(const int* __restrict__ ids,
                                                 int* __restrict__ list,
                                                 int* __restrict__ counter) {
  int t = threadIdx.x;
  int f = 0;
  #pragma unroll
  for (int j = 0; j < 16; ++j) f |= ids[2 * (t * 16 + j) + 1];
  int anyodd = __syncthreads_or(f);

  int i = blockIdx.x * 256 + t;
  int v = anyodd ? ids[i] : ids[2 * i];
  bool act = (v == 1);
  unsigned long long mask = __ballot(act);
  int lane = t & 63;
  int base = 0;
  if (lane == 0) base = atomicAdd(counter, __popcll(mask));
  base = __shfl(base, 0);
  if (act) {
    int off = __popcll(mask & ((1ull << lane) - 1ull));
    list[base + off] = i;
  }
}

// ------------------- codebook -> bf16 + per-codeword ||c||^2 ---------------
__global__ __launch_bounds__(256) void k_prep_cb(const float* __restrict__ cb,
                                                 unsigned short* __restrict__ cbb,
                                                 float* __restrict__ csq) {
  int c = blockIdx.x * 4 + (threadIdx.x >> 6);
  int lane = threadIdx.x & 63;
  const float4* src = (const float4*)(cb + (size_t)c * H);
  float ss = 0.f;
  #pragma unroll
  for (int i = 0; i < 4; ++i) {
    float4 v = src[lane + 64 * i];
    ss += v.x * v.x + v.y * v.y + v.z * v.z + v.w * v.w;
    ushort4 p;
    p.x = f2bf(v.x); p.y = f2bf(v.y); p.z = f2bf(v.z); p.w = f2bf(v.w);
    *(ushort4*)(cbb + (size_t)c * H + (size_t)(lane + 64 * i) * 4) = p;
  }
  #pragma unroll
  for (int d = 1; d < 64; d <<= 1) ss += __shfl_xor(ss, d);
  if (lane == 0) csq[c] = ss;
}

// --------------------- W [H,C] fp32 -> W^T [C,H] bf16 ----------------------
__global__ __launch_bounds__(256) void k_prep_w(const float* __restrict__ W,
                                                unsigned short* __restrict__ Wtb) {
  __shared__ float tile[64][68];
  int c0 = blockIdx.x * 64, k0 = blockIdx.y * 64;
  int r = threadIdx.x >> 2, q = threadIdx.x & 3;
  const float4* src = (const float4*)(W + (size_t)(k0 + r) * CBN + c0);
  #pragma unroll
  for (int i = 0; i < 4; ++i) {
    float4 v = src[q * 4 + i];
    *(float4*)&tile[r][q * 16 + i * 4] = v;
  }
  __syncthreads();
  unsigned short* dst = Wtb + (size_t)(c0 + r) * H + k0;
  #pragma unroll
  for (int i = 0; i < 4; ++i) {
    ushort4 p;
    p.x = f2bf(tile[q * 16 + i * 4 + 0][r]);
    p.y = f2bf(tile[q * 16 + i * 4 + 1][r]);
    p.z = f2bf(tile[q * 16 + i * 4 + 2][r]);
    p.w = f2bf(tile[q * 16 + i * 4 + 3][r]);
    *(ushort4*)(dst + q * 16 + i * 4) = p;
  }
}

// --------- gather active tokens -> bf16 rows + exact fp32 ||t||^2 ----------
__global__ __launch_bounds__(256) void k_prep_a(
    const float* __restrict__ hs, const float* __restrict__ tg,
    const int* __restrict__ list, const int* __restrict__ counter,
    unsigned short* __restrict__ Ahs, unsigned short* __restrict__ Atg,
    float* __restrict__ tsq) {
  const int n = *counter;
  const int n_pad = (n + MT - 1) & ~(MT - 1);
  const int ga = blockIdx.x * 4 + (threadIdx.x >> 6);
  if (ga >= n_pad) return;
  const int lane = threadIdx.x & 63;
  const int tok = list[(ga < n) ? ga : 0];
  const float4* h4 = (const float4*)(hs + (size_t)tok * H);
  const float4* t4 = (const float4*)(tg + (size_t)tok * H);
  unsigned short* ah = Ahs + (size_t)ga * H;
  unsigned short* at = Atg + (size_t)ga * H;
  float ss = 0.f;
  #pragma unroll
  for (int i = 0; i < 4; ++i) {
    float4 v = h4[lane + 64 * i];
    ushort4 p;
    p.x = f2bf(v.x); p.y = f2bf(v.y); p.z = f2bf(v.z); p.w = f2bf(v.w);
    *(ushort4*)(ah + (size_t)(lane + 64 * i) * 4) = p;
    float4 u = t4[lane + 64 * i];
    ss += u.x * u.x + u.y * u.y + u.z * u.z + u.w * u.w;
    ushort4 q;
    q.x = f2bf(u.x); q.y = f2bf(u.y); q.z = f2bf(u.z); q.w = f2bf(u.w);
    *(ushort4*)(at + (size_t)(lane + 64 * i) * 4) = q;
  }
  #pragma unroll
  for (int d = 1; d < 64; d <<= 1) ss += __shfl_xor(ss, d);
  if (lane == 0) tsq[ga] = ss;
}

// per-wave DMA batch: 8 loads (4 A + 4 B interleaved) into buffer pb
#define ISSUE_BATCH(Ag, Bg, kc, pb)                                       \
  do {                                                                    \
    const size_t koff = (size_t)((kc) * BK + cg * 8);                     \
    _Pragma("unroll")                                                     \
    for (int i_ = 0; i_ < 4; ++i_) {                                      \
      const int li_ = w + 4 * i_;                                         \
      const size_t goff_ = (size_t)(li_ * 8 + rsub) * H + koff;           \
      load_lds16((Ag) + rowA0H + goff_, &sA[pb][li_ * 512]);              \
      load_lds16((Bg) + colB0H + goff_, &sB[pb][li_ * 512]);              \
    }                                                                     \
  } while (0)

// ---------------- split kernel 1: cross GEMM -> bf16 ct blobs --------------
__global__ __launch_bounds__(256, 2) void k_cross(
    const unsigned short* __restrict__ Atg, const unsigned short* __restrict__ Cbb,
    const float* __restrict__ csq, const int* __restrict__ counter,
    unsigned short* __restrict__ ctB) {
  const int n = *counter;
  int tilex, tiley;
  tile_map(&tilex, &tiley);
  if (tilex * MT >= n) return;

  __shared__ __align__(16) unsigned short sA[2][MT * BK];
  __shared__ __align__(16) unsigned short sB[2][NTILE * BK];

  const int tid  = threadIdx.x;
  const int w    = tid >> 6, lane = tid & 63;
  const int wr   = w >> 1,   wc   = w & 1;
  const int quad = lane >> 4, lcol = lane & 15;
  const int swz  = lcol & 7;
  const int rsub = lane >> 3;
  const int cg   = (lane & 7) ^ rsub;
  const size_t rowA0H = (size_t)tilex * MT * H;
  const size_t colB0H = (size_t)tiley * NTILE * H;

  f32x4 acc[4][4];
  #pragma unroll
  for (int mb = 0; mb < 4; ++mb)
    #pragma unroll
    for (int nb = 0; nb < 4; ++nb) acc[mb][nb] = (f32x4){0.f, 0.f, 0.f, 0.f};

  ISSUE_BATCH(Atg, Cbb, 0, 0);
  #pragma unroll
  for (int kc = 0; kc < NKC; ++kc) {
    const int cur = kc & 1;
    if (kc + 1 < NKC) { ISSUE_BATCH(Atg, Cbb, kc + 1, cur ^ 1); wait_vm8(); }
    else              { wait_vm0(); }
    barrier_raw();
    #pragma unroll
    for (int ks = 0; ks < 2; ++ks) {
      const int cA = (((ks * 4 + quad) ^ swz) * 8);
      s16x8 af[4], bf[4];
      #pragma unroll
      for (int mb = 0; mb < 4; ++mb)
        af[mb] = *(const s16x8*)&sA[cur][(wr * 64 + mb * 16 + lcol) * BK + cA];
      #pragma unroll
      for (int nb = 0; nb < 4; ++nb)
        bf[nb] = *(const s16x8*)&sB[cur][(wc * 64 + nb * 16 + lcol) * BK + cA];
      #pragma unroll
      for (int mb = 0; mb < 4; ++mb)
        #pragma unroll
        for (int nb = 0; nb < 4; ++nb)
          acc[mb][nb] = mfma16(af[mb], bf[nb], acc[mb][nb]);
    }
    barrier_raw();   // LDS reads done before next overwrite of cur^1... (kc-1 buf)
  }

  // epilogue: ct = csq - 2*cross - CTC as bf16 blobs, fully coalesced:
  // blob elem layout [bid][wave][e<8][lane][8], e = nb*2 + (mb>>1)
  const int bid = tiley * 64 + tilex;
  unsigned short* blob = ctB + (size_t)bid * 16384 + (size_t)w * 4096;
  float cqc[4];
  #pragma unroll
  for (int nb = 0; nb < 4; ++nb)
    cqc[nb] = csq[tiley * NTILE + wc * 64 + nb * 16 + lcol] - CTC;
  #pragma unroll
  for (int nb = 0; nb < 4; ++nb) {
    #pragma unroll
    for (int mbp = 0; mbp < 2; ++mbp) {
      u16x8 st;
      #pragma unroll
      for (int hh = 0; hh < 2; ++hh) {
        const int mb = mbp * 2 + hh;
        #pragma unroll
        for (int j = 0; j < 4; ++j)
          st[hh * 4 + j] = f2bf(cqc[nb] - 2.f * acc[mb][nb][j]);
      }
      const int e = nb * 2 + mbp;
      *(u16x8*)(blob + e * 512 + lane * 8) = st;
    }
  }
}

// -------- split kernel 2: logits GEMM + softmax partials (reads blobs) -----
__global__ __launch_bounds__(256, 2) void k_logit(
    const unsigned short* __restrict__ Ahs, const unsigned short* __restrict__ Wtb,
    const float* __restrict__ bias, const unsigned short* __restrict__ ctB,
    const int* __restrict__ counter,
    float* __restrict__ pm, float* __restrict__ pl, float* __restrict__ ps) {
  const int n = *counter;
  int tilex, tiley;
  tile_map(&tilex, &tiley);
  if (tilex * MT >= n) return;

  __shared__ __align__(16) unsigned short sA[2][MT * BK];
  __shared__ __align__(16) unsigned short sB[2][NTILE * BK];

  const int tid  = threadIdx.x;
  const int w    = tid >> 6, lane = tid & 63;
  const int wr   = w >> 1,   wc   = w & 1;
  const int quad = lane >> 4, lcol = lane & 15;
  const int swz  = lcol & 7;
  const int rsub = lane >> 3;
  const int cg   = (lane & 7) ^ rsub;
  const size_t rowA0H = (size_t)tilex * MT * H;
  const size_t colB0H = (size_t)tiley * NTILE * H;

  f32x4 acc[4][4];
  #pragma unroll
  for (int mb = 0; mb < 4; ++mb)
    #pragma unroll
    for (int nb = 0; nb < 4; ++nb) acc[mb][nb] = (f32x4){0.f, 0.f, 0.f, 0.f};

  ISSUE_BATCH(Ahs, Wtb, 0, 0);
  #pragma unroll
  for (int kc = 0; kc < NKC; ++kc) {
    const int cur = kc & 1;
    if (kc + 1 < NKC) { ISSUE_BATCH(Ahs, Wtb, kc + 1, cur ^ 1); wait_vm8(); }
    else              { wait_vm0(); }
    barrier_raw();
    #pragma unroll
    for (int ks = 0; ks < 2; ++ks) {
      const int cA = (((ks * 4 + quad) ^ swz) * 8);
      s16x8 af[4], bf[4];
      #pragma unroll
      for (int mb = 0; mb < 4; ++mb)
        af[mb] = *(const s16x8*)&sA[cur][(wr * 64 + mb * 16 + lcol) * BK + cA];
      #pragma unroll
      for (int nb = 0; nb < 4; ++nb)
        bf[nb] = *(const s16x8*)&sB[cur][(wc * 64 + nb * 16 + lcol) * BK + cA];
      #pragma unroll
      for (int mb = 0; mb < 4; ++mb)
        #pragma unroll
        for (int nb = 0; nb < 4; ++nb)
          acc[mb][nb] = mfma16(af[mb], bf[nb], acc[mb][nb]);
    }
    barrier_raw();
  }

  // epilogue: read ct blob back (coalesced), softmax partial per 64-col strip
  const int bid = tiley * 64 + tilex;
  const unsigned short* blob = ctB + (size_t)bid * 16384 + (size_t)w * 4096;
  u16x8 c8[8];
  #pragma unroll
  for (int e = 0; e < 8; ++e)
    c8[e] = *(const u16x8*)(blob + e * 512 + lane * 8);

  float bv[4];
  #pragma unroll
  for (int nb = 0; nb < 4; ++nb)
    bv[nb] = bias[tiley * NTILE + wc * 64 + nb * 16 + lcol];

  const int chunk = tiley * 2 + wc;
  #pragma unroll
  for (int mb = 0; mb < 4; ++mb) {
    #pragma unroll
    for (int j = 0; j < 4; ++j) {
      float lg[4], ct[4];
      #pragma unroll
      for (int nb = 0; nb < 4; ++nb) {
        lg[nb] = acc[mb][nb][j] + bv[nb];
        ct[nb] = bf2f(c8[nb * 2 + (mb >> 1)][(mb & 1) * 4 + j]);
      }
      float tmax = fmaxf(fmaxf(lg[0], lg[1]), fmaxf(lg[2], lg[3]));
      #pragma unroll
      for (int d = 1; d < 16; d <<= 1) tmax = fmaxf(tmax, __shfl_xor(tmax, d));
      float le = 0.f, se = 0.f;
      #pragma unroll
      for (int nb = 0; nb < 4; ++nb) {
        const float e = __expf(lg[nb] - tmax);
        le += e; se += e * ct[nb];
      }
      #pragma unroll
      for (int d = 1; d < 16; d <<= 1) {
        le += __shfl_xor(le, d);
        se += __shfl_xor(se, d);
      }
      if (lcol == 0) {
        const int row = tilex * MT + wr * 64 + mb * 16 + quad * 4 + j;
        pm[chunk * NTOK + row] = tmax;
        pl[chunk * NTOK + row] = le;
        ps[chunk * NTOK + row] = se;
      }
    }
  }
}

// ---------------- R2 fused dual-GEMM (ws-size fallback path) ---------------
__global__ __launch_bounds__(256, 2) void k_fused(
    const unsigned short* __restrict__ Ahs, const unsigned short* __restrict__ Atg,
    const unsigned short* __restrict__ Wtb, const unsigned short* __restrict__ Cbb,
    const float* __restrict__ bias, const float* __restrict__ csq,
    const int* __restrict__ counter,
    float* __restrict__ pm, float* __restrict__ pl, float* __restrict__ ps) {
  const int n = *counter;
  const int tilex = blockIdx.x;
  if (tilex * MT >= n) return;
  const int tiley = blockIdx.y;

  __shared__ __align__(16) unsigned short sA1[MT * BK];
  __shared__ __align__(16) unsigned short sA2[MT * BK];
  __shared__ __align__(16) unsigned short sB1[NTILE * BK];
  __shared__ __align__(16) unsigned short sB2[NTILE * BK];

  const int tid  = threadIdx.x;
  const int w    = tid >> 6, lane = tid & 63;
  const int wr   = w >> 1,   wc   = w & 1;
  const int quad = lane >> 4, lcol = lane & 15;
  const int swz  = lcol & 7;
  const int rsub = lane >> 3;
  const int cg   = (lane & 7) ^ rsub;
  const size_t rowA0H = (size_t)tilex * MT * H;
  const size_t colB0H = (size_t)tiley * NTILE * H;

  f32x4 acc1[4][4], acc2[4][4];
  #pragma unroll
  for (int mb = 0; mb < 4; ++mb)
    #pragma unroll
    for (int nb = 0; nb < 4; ++nb) {
      acc1[mb][nb] = (f32x4){0.f, 0.f, 0.f, 0.f};
      acc2[mb][nb] = (f32x4){0.f, 0.f, 0.f, 0.f};
    }

  for (int kc = 0; kc < NKC; ++kc) {
    #pragma unroll
    for (int i = 0; i < 4; ++i) {
      const int li  = w + 4 * i;
      const int rit = li * 8 + rsub;
      const size_t goff = (size_t)rit * H + (size_t)(kc * BK + cg * 8);
      load_lds16(Ahs + rowA0H + goff, &sA1[li * 512]);
      load_lds16(Atg + rowA0H + goff, &sA2[li * 512]);
      load_lds16(Wtb + colB0H + goff, &sB1[li * 512]);
      load_lds16(Cbb + colB0H + goff, &sB2[li * 512]);
    }
    __syncthreads();
    #pragma unroll
    for (int ks = 0; ks < 2; ++ks) {
      const int cA = (((ks * 4 + quad) ^ swz) * 8);
      {
        s16x8 af[4], bf[4];
        #pragma unroll
        for (int mb = 0; mb < 4; ++mb)
          af[mb] = *(const s16x8*)&sA1[(wr * 64 + mb * 16 + lcol) * BK + cA];
        #pragma unroll
        for (int nb = 0; nb < 4; ++nb)
          bf[nb] = *(const s16x8*)&sB1[(wc * 64 + nb * 16 + lcol) * BK + cA];
        #pragma unroll
        for (int mb = 0; mb < 4; ++mb)
          #pragma unroll
          for (int nb = 0; nb < 4; ++nb)
            acc1[mb][nb] = mfma16(af[mb], bf[nb], acc1[mb][nb]);
      }
      {
        s16x8 af[4], bf[4];
        #pragma unroll
        for (int mb = 0; mb < 4; ++mb)
          af[mb] = *(const s16x8*)&sA2[(wr * 64 + mb * 16 + lcol) * BK + cA];
        #pragma unroll
        for (int nb = 0; nb < 4; ++nb)
          bf[nb] = *(const s16x8*)&sB2[(wc * 64 + nb * 16 + lcol) * BK + cA];
        #pragma unroll
        for (int mb = 0; mb < 4; ++mb)
          #pragma unroll
          for (int nb = 0; nb < 4; ++nb)
            acc2[mb][nb] = mfma16(af[mb], bf[nb], acc2[mb][nb]);
      }
    }
    __syncthreads();
  }

  float bv[4], cq[4];
  #pragma unroll
  for (int nb = 0; nb < 4; ++nb) {
    const int col = tiley * NTILE + wc * 64 + nb * 16 + lcol;
    bv[nb] = bias[col];
    cq[nb] = csq[col];
  }
  const int chunk = tiley * 2 + wc;
  #pragma unroll
  for (int mb = 0; mb < 4; ++mb) {
    #pragma unroll
    for (int j = 0; j < 4; ++j) {
      float lg[4], ct[4];
      #pragma unroll
      for (int nb = 0; nb < 4; ++nb) {
        lg[nb] = acc1[mb][nb][j] + bv[nb];
        ct[nb] = cq[nb] - 2.f * acc2[mb][nb][j];
      }
      float tmax = fmaxf(fmaxf(lg[0], lg[1]), fmaxf(lg[2], lg[3]));
      #pragma unroll
      for (int d = 1; d < 16; d <<= 1) tmax = fmaxf(tmax, __shfl_xor(tmax, d));
      float le = 0.f, se = 0.f;
      #pragma unroll
      for (int nb = 0; nb < 4; ++nb) {
        const float e = __expf(lg[nb] - tmax);
        le += e; se += e * ct[nb];
      }
      #pragma unroll
      for (int d = 1; d < 16; d <<= 1) {
        le += __shfl_xor(le, d);
        se += __shfl_xor(se, d);
      }
      if (lcol == 0) {
        const int row = tilex * MT + wr * 64 + mb * 16 + quad * 4 + j;
        pm[chunk * NTOK + row] = tmax;
        pl[chunk * NTOK + row] = le;
        ps[chunk * NTOK + row] = se;
      }
    }
  }
}

// ----------------- merge strip partials -> scalar loss ---------------------
__global__ __launch_bounds__(256) void k_merge(
    const int* __restrict__ counter, const float* __restrict__ tsq,
    const float* __restrict__ pm, const float* __restrict__ pl,
    const float* __restrict__ ps, float* __restrict__ out, float addc) {
  const int n = *counter;
  const int ga = blockIdx.x * 256 + threadIdx.x;
  float val = 0.f;
  if (ga < n) {
    float M = -1e30f;
    for (int j = 0; j < NCHK; ++j) M = fmaxf(M, pm[j * NTOK + ga]);
    float L = 0.f, S = 0.f;
    for (int j = 0; j < NCHK; ++j) {
      const float e = __expf(pm[j * NTOK + ga] - M);
      L += pl[j * NTOK + ga] * e;
      S += ps[j * NTOK + ga] * e;
    }
    val = (tsq[ga] + addc + S / L) * (LOSSW / (float)H);
  }
  #pragma unroll
  for (int d = 1; d < 64; d <<= 1) val += __shfl_xor(val, d);
  __shared__ float wsum[4];
  if ((threadIdx.x & 63) == 0) wsum[threadIdx.x >> 6] = val;
  __syncthreads();
  if (threadIdx.x == 0)
    atomicAdd(out, wsum[0] + wsum[1] + wsum[2] + wsum[3]);
}

// ---------------------------------------------------------------------------
extern "C" void kernel_launch(void* const* d_in, const int* in_sizes, int n_in,
                              void* d_out, int out_size, void* d_ws, size_t ws_size,
                              hipStream_t stream) {
  const float* hs   = (const float*)d_in[0];
  const int*   ids  = (const int*)d_in[1];
  const float* tg   = (const float*)d_in[2];
  const float* cb   = (const float*)d_in[3];
  const float* W    = (const float*)d_in[4];
  const float* bias = (const float*)d_in[5];

  char* ws = (char*)d_ws;
  constexpr size_t OFF_CNT  = 0;
  constexpr size_t OFF_WTB  = 256;
  constexpr size_t OFF_CBB  = OFF_WTB  + (size_t)CBN * H * 2;
  constexpr size_t OFF_AHS  = OFF_CBB  + (size_t)CBN * H * 2;
  constexpr size_t OFF_ATG  = OFF_AHS  + (size_t)NTOK * H * 2;
  constexpr size_t OFF_CSQ  = OFF_ATG  + (size_t)NTOK * H * 2;
  constexpr size_t OFF_TSQ  = OFF_CSQ  + (size_t)CBN * 4;
  constexpr size_t OFF_LIST = OFF_TSQ  + (size_t)NTOK * 4;
  constexpr size_t OFF_PM   = OFF_LIST + (size_t)NTOK * 4;
  constexpr size_t OFF_PL   = OFF_PM   + (size_t)NCHK * NTOK * 4;
  constexpr size_t OFF_PS   = OFF_PL   + (size_t)NCHK * NTOK * 4;
  constexpr size_t OFF_CTT  = OFF_PS   + (size_t)NCHK * NTOK * 4;
  constexpr size_t REQ_SPLIT = OFF_CTT + (size_t)CBN * NTOK * 2;   // ~204 MiB

  int*            counter = (int*)(ws + OFF_CNT);
  unsigned short* Wtb     = (unsigned short*)(ws + OFF_WTB);
  unsigned short* Cbb     = (unsigned short*)(ws + OFF_CBB);
  unsigned short* Ahs     = (unsigned short*)(ws + OFF_AHS);
  unsigned short* Atg     = (unsigned short*)(ws + OFF_ATG);
  float*          csq     = (float*)(ws + OFF_CSQ);
  float*          tsq     = (float*)(ws + OFF_TSQ);
  int*            list    = (int*)(ws + OFF_LIST);
  float*          pm      = (float*)(ws + OFF_PM);
  float*          pl      = (float*)(ws + OFF_PL);
  float*          ps      = (float*)(ws + OFF_PS);
  unsigned short* ctB     = (unsigned short*)(ws + OFF_CTT);

  hipMemsetAsync(counter, 0, sizeof(int), stream);
  hipMemsetAsync(d_out, 0, sizeof(float), stream);

  k_compact<<<NTOK / 256, 256, 0, stream>>>(ids, list, counter);
  k_prep_cb<<<CBN / 4, 256, 0, stream>>>(cb, Cbb, csq);
  k_prep_w<<<dim3(CBN / 64, H / 64), 256, 0, stream>>>(W, Wtb);
  k_prep_a<<<NTOK / 4, 256, 0, stream>>>(hs, tg, list, counter, Ahs, Atg, tsq);

  if (ws_size >= REQ_SPLIT) {
    k_cross<<<dim3(NTOK / MT, CBN / NTILE), 256, 0, stream>>>(
        Atg, Cbb, csq, counter, ctB);
    k_logit<<<dim3(NTOK / MT, CBN / NTILE), 256, 0, stream>>>(
        Ahs, Wtb, bias, ctB, counter, pm, pl, ps);
    k_merge<<<NTOK / 256, 256, 0, stream>>>(counter, tsq, pm, pl, ps,
                                            (float*)d_out, CTC);
  } else {
    k_fused<<<dim3(NTOK / MT, CBN / NTILE), 256, 0, stream>>>(
        Ahs, Atg, Wtb, Cbb, bias, csq, counter, pm, pl, ps);
    k_merge<<<NTOK / 256, 256, 0, stream>>>(counter, tsq, pm, pl, ps,
                                            (float*)d_out, 0.0f);
  }
}

// Round 5
// 318.322 us; speedup vs baseline: 1.4573x; 1.2080x over previous
//
#include <hip/hip_runtime.h>
#include <hip/hip_bf16.h>

// ---------------------------------------------------------------------------
// TokenDiscrepancyLoss: loss = 0.1 * sum_{mask} [ (||t||^2 + sum_c p_c (||c||^2 - 2 t.c)) / H ]
// with p = softmax(hs @ W + b) over C=8192.
//
// R5: fp8(e4m3) GEMMs. All staging pre-converted to k-major slabs
// [panel][kc][granule g(8)][row(128)][8B] so global->LDS DMA is a contiguous
// copy and LDS fragment reads (ds_read_b64) are bank-conflict-free.
// Double-buffered LDS (32 KB) + vmcnt(4) pipeline -> 4-5 blocks/CU.
// Dispatches: memset, prep1(compact+cb+W), prep_a, cross, logit, merge.
// ---------------------------------------------------------------------------

#define H        1024
#define CBN      8192
#define NTOK     8192
#define MT       128
#define NTILE    128
#define BK       64
#define NKC      16               // H / BK
#define NCHK     128              // partial strips (one per 64-col wave tile)
#define LOSSW    0.1f
#define CTC      1024.0f          // centering for bf16 ct storage
#define WSCALE   16.0f            // W pre-scale (pow2) for fp8 range
#define WINV     0.0625f
#define SLAB     131072           // bytes per 128-row panel: 16kc*8g*128r*8B

typedef __attribute__((ext_vector_type(4))) float f32x4;

__device__ __forceinline__ unsigned short f2bf(float f) {
  union { float f; unsigned u; } x; x.f = f;
  return (unsigned short)((x.u + 0x7FFFu + ((x.u >> 16) & 1u)) >> 16); // RNE
}
__device__ __forceinline__ float bf2f(unsigned short u) {
  union { unsigned u; float f; } x; x.u = (unsigned)u << 16;
  return x.f;
}

// ---- fp32 -> fp8 e4m3fn (OCP) ----
__device__ unsigned char f2fp8_sw(float f) {
  float a = fabsf(f);
  unsigned s = f < 0.f ? 0x80u : 0u;
  if (!(a < 448.f)) return (unsigned char)(s | 0x7Eu);
  if (a < 0.0009765625f) return (unsigned char)s;   // < 2^-10 -> 0
  int e; float m = frexpf(a, &e);                   // a = m*2^e, m in [.5,1)
  int te = e - 1;
  if (te < -6) {                                    // subnormal, ulp 2^-9
    int q = (int)rintf(a * 512.f); if (q > 7) q = 7;
    return (unsigned char)(s | q);
  }
  int q = (int)rintf((2.f * m - 1.f) * 8.f);        // 0..8
  int E = te + 7, M = q;
  if (q == 8) { E += 1; M = 0; }
  if (E > 15) return (unsigned char)(s | 0x7Eu);
  return (unsigned char)(s | (E << 3) | M);
}
__device__ __forceinline__ unsigned pack4(float a, float b, float c, float d) {
#if __has_builtin(__builtin_amdgcn_cvt_pk_fp8_f32)
  int r = __builtin_amdgcn_cvt_pk_fp8_f32(a, b, 0, false);
  r     = __builtin_amdgcn_cvt_pk_fp8_f32(c, d, r, true);
  return (unsigned)r;
#else
  return (unsigned)f2fp8_sw(a) | ((unsigned)f2fp8_sw(b) << 8) |
         ((unsigned)f2fp8_sw(c) << 16) | ((unsigned)f2fp8_sw(d) << 24);
#endif
}

// async global->LDS DMA, 16B/lane; LDS dest = wave-uniform base + lane*16
__device__ __forceinline__ void load_lds16(const void* g, void* l) {
  __builtin_amdgcn_global_load_lds((const __attribute__((address_space(1))) void*)g,
                                   (__attribute__((address_space(3))) void*)l,
                                   16, 0, 0);
}
__device__ __forceinline__ void wait_vm4() { asm volatile("s_waitcnt vmcnt(4)" ::: "memory"); }
__device__ __forceinline__ void wait_vm0() { asm volatile("s_waitcnt vmcnt(0)" ::: "memory"); }
__device__ __forceinline__ void barrier_raw() { asm volatile("s_barrier" ::: "memory"); }

// XCD-aware tile mapping (identical in cross/logit so ct blobs line up)
__device__ __forceinline__ void tile_map(int* tilex, int* tiley) {
  const int flat = blockIdx.y * 64 + blockIdx.x;
  const int xcd = flat & 7, loc = flat >> 3;
  *tiley = xcd * 8 + (loc & 7);
  *tilex = loc >> 3;
}

// ---------------- prep1: compact (32 blk) + W (1024 blk) + cb (256 blk) ----
__global__ __launch_bounds__(256) void k_prep1(
    const int* __restrict__ ids, const float* __restrict__ cb,
    const float* __restrict__ W,
    int* __restrict__ list, int* __restrict__ counter,
    float* __restrict__ csq,
    unsigned char* __restrict__ Wtb, unsigned char* __restrict__ Cbb) {
  __shared__ __align__(16) unsigned char tile[8192];
  const int b = blockIdx.x, t = threadIdx.x;
  if (b < 32) {
    // ---- compact active tokens (int32/int64 layout autodetect) ----
    int f = 0;
    #pragma unroll
    for (int j = 0; j < 16; ++j) f |= ids[2 * (t * 16 + j) + 1];
    int anyodd = __syncthreads_or(f);
    int i = b * 256 + t;
    int v = anyodd ? ids[i] : ids[2 * i];
    bool act = (v == 1);
    unsigned long long mask = __ballot(act);
    int lane = t & 63;
    int base = 0;
    if (lane == 0) base = atomicAdd(counter, __popcll(mask));
    base = __shfl(base, 0);
    if (act) list[base + __popcll(mask & ((1ull << lane) - 1ull))] = i;
  } else if (b < 1056) {
    // ---- W [H][C] fp32 -> fp8 slab [tiley][kc][g][c][8], scaled x16 ----
    const int q = b - 32, tiley = q >> 4, kc = q & 15;
    const int c = t & 127, gh = t >> 7;
    unsigned char* dst = Wtb + (size_t)tiley * SLAB + (size_t)kc * 8192;
    #pragma unroll
    for (int gi = 0; gi < 4; ++gi) {
      const int g = gh * 4 + gi;
      const float* wp = W + (size_t)(kc * 64 + g * 8) * CBN + tiley * 128 + c;
      float v[8];
      #pragma unroll
      for (int j = 0; j < 8; ++j) v[j] = wp[(size_t)j * CBN] * WSCALE;
      uint2 pk;
      pk.x = pack4(v[0], v[1], v[2], v[3]);
      pk.y = pack4(v[4], v[5], v[6], v[7]);
      *(uint2*)(dst + g * 1024 + c * 8) = pk;
    }
  } else {
    // ---- codebook [C][H] fp32 -> fp8 slab + csq partials ----
    const int q = b - 1056, tiley = q >> 2, kcg = q & 3;
    const int r = t >> 1, h = t & 1;
    const int c = tiley * 128 + r;
    float ss = 0.f;
    for (int kk = 0; kk < 4; ++kk) {
      const int kc = kcg * 4 + kk;
      const float4* s4 = (const float4*)(cb + (size_t)c * H + kc * 64 + h * 32);
      #pragma unroll
      for (int i = 0; i < 4; ++i) {
        float4 va = s4[2 * i], vb = s4[2 * i + 1];
        ss += va.x * va.x + va.y * va.y + va.z * va.z + va.w * va.w;
        ss += vb.x * vb.x + vb.y * vb.y + vb.z * vb.z + vb.w * vb.w;
        uint2 pk;
        pk.x = pack4(va.x, va.y, va.z, va.w);
        pk.y = pack4(vb.x, vb.y, vb.z, vb.w);
        *(uint2*)&tile[(h * 4 + i) * 1024 + r * 8] = pk;
      }
      __syncthreads();
      const uint4* tp = (const uint4*)tile;
      uint4 x0 = tp[t * 2], x1 = tp[t * 2 + 1];
      unsigned char* dst = Cbb + (size_t)tiley * SLAB + (size_t)kc * 8192 + t * 32;
      *(uint4*)dst = x0; *(uint4*)(dst + 16) = x1;
      __syncthreads();
    }
    ss += __shfl_xor(ss, 1);
    if (h == 0) atomicAdd(&csq[c], ss);
  }
}

// ------- gather active tokens -> fp8 slabs (hs, tg) + fp32 ||t||^2 ---------
__global__ __launch_bounds__(256) void k_prep_a(
    const float* __restrict__ hs, const float* __restrict__ tg,
    const int* __restrict__ list, const int* __restrict__ counter,
    unsigned char* __restrict__ Ahs, unsigned char* __restrict__ Atg,
    float* __restrict__ tsq) {
  const int n = *counter;
  const int n_pad = (n + MT - 1) & ~(MT - 1);
  const int tilex = blockIdx.x >> 2, kcg = blockIdx.x & 3;
  if (tilex * MT >= n_pad) return;
  __shared__ int stok[128];
  __shared__ __align__(16) unsigned char tile[8192];
  const int t = threadIdx.x, r = t >> 1, h = t & 1;
  if (t < 128) {
    int ga = tilex * MT + t;
    stok[t] = list[(ga < n) ? ga : 0];
  }
  __syncthreads();
  const size_t srow = (size_t)stok[r] * H;
  float ss = 0.f;
  for (int kk = 0; kk < 4; ++kk) {
    const int kc = kcg * 4 + kk;
    // ---- hs ----
    {
      const float4* s4 = (const float4*)(hs + srow + kc * 64 + h * 32);
      #pragma unroll
      for (int i = 0; i < 4; ++i) {
        float4 va = s4[2 * i], vb = s4[2 * i + 1];
        uint2 pk;
        pk.x = pack4(va.x, va.y, va.z, va.w);
        pk.y = pack4(vb.x, vb.y, vb.z, vb.w);
        *(uint2*)&tile[(h * 4 + i) * 1024 + r * 8] = pk;
      }
      __syncthreads();
      const uint4* tp = (const uint4*)tile;
      uint4 x0 = tp[t * 2], x1 = tp[t * 2 + 1];
      unsigned char* dst = Ahs + (size_t)tilex * SLAB + (size_t)kc * 8192 + t * 32;
      *(uint4*)dst = x0; *(uint4*)(dst + 16) = x1;
      __syncthreads();
    }
    // ---- tg (+ exact fp32 sum of squares) ----
    {
      const float4* s4 = (const float4*)(tg + srow + kc * 64 + h * 32);
      #pragma unroll
      for (int i = 0; i < 4; ++i) {
        float4 va = s4[2 * i], vb = s4[2 * i + 1];
        ss += va.x * va.x + va.y * va.y + va.z * va.z + va.w * va.w;
        ss += vb.x * vb.x + vb.y * vb.y + vb.z * vb.z + vb.w * vb.w;
        uint2 pk;
        pk.x = pack4(va.x, va.y, va.z, va.w);
        pk.y = pack4(vb.x, vb.y, vb.z, vb.w);
        *(uint2*)&tile[(h * 4 + i) * 1024 + r * 8] = pk;
      }
      __syncthreads();
      const uint4* tp = (const uint4*)tile;
      uint4 x0 = tp[t * 2], x1 = tp[t * 2 + 1];
      unsigned char* dst = Atg + (size_t)tilex * SLAB + (size_t)kc * 8192 + t * 32;
      *(uint4*)dst = x0; *(uint4*)(dst + 16) = x1;
      __syncthreads();
    }
  }
  ss += __shfl_xor(ss, 1);
  if (h == 0) atomicAdd(&tsq[tilex * MT + r], ss);
}

// per-wave DMA batch: 4 contiguous 1 KB wave-loads (2 A granule-rows + 2 B)
#define ISSUE(Aslab, Bslab, kc, pb)                                        \
  do {                                                                     \
    const unsigned char* ap_ = (Aslab) + Aoff + (size_t)(kc) * 8192 + lane * 16; \
    const unsigned char* bp_ = (Bslab) + Boff + (size_t)(kc) * 8192 + lane * 16; \
    load_lds16(ap_ + w * 1024,       &sA[pb][w * 1024]);                   \
    load_lds16(ap_ + (w + 4) * 1024, &sA[pb][(w + 4) * 1024]);             \
    load_lds16(bp_ + w * 1024,       &sB[pb][w * 1024]);                   \
    load_lds16(bp_ + (w + 4) * 1024, &sB[pb][(w + 4) * 1024]);             \
  } while (0)

// ---------------- split kernel 1: cross GEMM -> bf16 ct blobs --------------
__global__ __launch_bounds__(256, 4) void k_cross(
    const unsigned char* __restrict__ Atg, const unsigned char* __restrict__ Cbb,
    const float* __restrict__ csq, const int* __restrict__ counter,
    unsigned short* __restrict__ ctB) {
  const int n = *counter;
  int tilex, tiley;
  tile_map(&tilex, &tiley);
  if (tilex * MT >= n) return;

  __shared__ __align__(16) unsigned char sA[2][8192];
  __shared__ __align__(16) unsigned char sB[2][8192];

  const int t = threadIdx.x;
  const int w = t >> 6, lane = t & 63;
  const int wr = w >> 1, wc = w & 1;
  const int quad = lane >> 4, lcol = lane & 15;
  const size_t Aoff = (size_t)tilex * SLAB;
  const size_t Boff = (size_t)tiley * SLAB;

  f32x4 acc[4][4];
  #pragma unroll
  for (int mb = 0; mb < 4; ++mb)
    #pragma unroll
    for (int nb = 0; nb < 4; ++nb) acc[mb][nb] = (f32x4){0.f, 0.f, 0.f, 0.f};

  ISSUE(Atg, Cbb, 0, 0);
  #pragma unroll
  for (int kc = 0; kc < NKC; ++kc) {
    const int cur = kc & 1;
    if (kc + 1 < NKC) { ISSUE(Atg, Cbb, kc + 1, cur ^ 1); wait_vm4(); }
    else              { wait_vm0(); }
    barrier_raw();
    #pragma unroll
    for (int ks = 0; ks < 2; ++ks) {
      const int gb = (ks * 4 + quad) * 1024;
      long aF[4], bF[4];
      #pragma unroll
      for (int mb = 0; mb < 4; ++mb)
        aF[mb] = *(const long*)&sA[cur][gb + (wr * 64 + mb * 16 + lcol) * 8];
      #pragma unroll
      for (int nb = 0; nb < 4; ++nb)
        bF[nb] = *(const long*)&sB[cur][gb + (wc * 64 + nb * 16 + lcol) * 8];
      #pragma unroll
      for (int mb = 0; mb < 4; ++mb)
        #pragma unroll
        for (int nb = 0; nb < 4; ++nb)
          acc[mb][nb] = __builtin_amdgcn_mfma_f32_16x16x32_fp8_fp8(
              aF[mb], bF[nb], acc[mb][nb], 0, 0, 0);
    }
    barrier_raw();
  }

  // ct = csq - 2*cross - CTC as bf16 blobs [bid][wave][e(8)][lane][8]
  const int bid = tiley * 64 + tilex;
  unsigned short* blob = ctB + (size_t)bid * 16384 + (size_t)w * 4096;
  float cqc[4];
  #pragma unroll
  for (int nb = 0; nb < 4; ++nb)
    cqc[nb] = csq[tiley * NTILE + wc * 64 + nb * 16 + lcol] - CTC;
  #pragma unroll
  for (int nb = 0; nb < 4; ++nb) {
    #pragma unroll
    for (int mbp = 0; mbp < 2; ++mbp) {
      ushort4 lo, hi;
      const int mb0 = mbp * 2;
      lo.x = f2bf(cqc[nb] - 2.f * acc[mb0][nb][0]);
      lo.y = f2bf(cqc[nb] - 2.f * acc[mb0][nb][1]);
      lo.z = f2bf(cqc[nb] - 2.f * acc[mb0][nb][2]);
      lo.w = f2bf(cqc[nb] - 2.f * acc[mb0][nb][3]);
      hi.x = f2bf(cqc[nb] - 2.f * acc[mb0 + 1][nb][0]);
      hi.y = f2bf(cqc[nb] - 2.f * acc[mb0 + 1][nb][1]);
      hi.z = f2bf(cqc[nb] - 2.f * acc[mb0 + 1][nb][2]);
      hi.w = f2bf(cqc[nb] - 2.f * acc[mb0 + 1][nb][3]);
      const int e = nb * 2 + mbp;
      *(ushort4*)(blob + e * 512 + lane * 8) = lo;
      *(ushort4*)(blob + e * 512 + lane * 8 + 4) = hi;
    }
  }
}

// -------- split kernel 2: logits GEMM + softmax partials (reads blobs) -----
__global__ __launch_bounds__(256, 4) void k_logit(
    const unsigned char* __restrict__ Ahs, const unsigned char* __restrict__ Wtb,
    const float* __restrict__ bias, const unsigned short* __restrict__ ctB,
    const int* __restrict__ counter,
    float* __restrict__ pm, float* __restrict__ pl, float* __restrict__ ps) {
  const int n = *counter;
  int tilex, tiley;
  tile_map(&tilex, &tiley);
  if (tilex * MT >= n) return;

  __shared__ __align__(16) unsigned char sA[2][8192];
  __shared__ __align__(16) unsigned char sB[2][8192];

  const int t = threadIdx.x;
  const int w = t >> 6, lane = t & 63;
  const int wr = w >> 1, wc = w & 1;
  const int quad = lane >> 4, lcol = lane & 15;
  const size_t Aoff = (size_t)tilex * SLAB;
  const size_t Boff = (size_t)tiley * SLAB;

  f32x4 acc[4][4];
  #pragma unroll
  for (int mb = 0; mb < 4; ++mb)
    #pragma unroll
    for (int nb = 0; nb < 4; ++nb) acc[mb][nb] = (f32x4){0.f, 0.f, 0.f, 0.f};

  ISSUE(Ahs, Wtb, 0, 0);
  #pragma unroll
  for (int kc = 0; kc < NKC; ++kc) {
    const int cur = kc & 1;
    if (kc + 1 < NKC) { ISSUE(Ahs, Wtb, kc + 1, cur ^ 1); wait_vm4(); }
    else              { wait_vm0(); }
    barrier_raw();
    #pragma unroll
    for (int ks = 0; ks < 2; ++ks) {
      const int gb = (ks * 4 + quad) * 1024;
      long aF[4], bF[4];
      #pragma unroll
      for (int mb = 0; mb < 4; ++mb)
        aF[mb] = *(const long*)&sA[cur][gb + (wr * 64 + mb * 16 + lcol) * 8];
      #pragma unroll
      for (int nb = 0; nb < 4; ++nb)
        bF[nb] = *(const long*)&sB[cur][gb + (wc * 64 + nb * 16 + lcol) * 8];
      #pragma unroll
      for (int mb = 0; mb < 4; ++mb)
        #pragma unroll
        for (int nb = 0; nb < 4; ++nb)
          acc[mb][nb] = __builtin_amdgcn_mfma_f32_16x16x32_fp8_fp8(
              aF[mb], bF[nb], acc[mb][nb], 0, 0, 0);
    }
    barrier_raw();
  }

  // epilogue: logits (undo W scale) + ct blob readback -> (m,l,s) per strip
  const int bid = tiley * 64 + tilex;
  const unsigned short* blob = ctB + (size_t)bid * 16384 + (size_t)w * 4096;
  ushort4 c8[8][2];
  #pragma unroll
  for (int e = 0; e < 8; ++e) {
    c8[e][0] = *(const ushort4*)(blob + e * 512 + lane * 8);
    c8[e][1] = *(const ushort4*)(blob + e * 512 + lane * 8 + 4);
  }
  float bv[4];
  #pragma unroll
  for (int nb = 0; nb < 4; ++nb)
    bv[nb] = bias[tiley * NTILE + wc * 64 + nb * 16 + lcol];

  const int chunk = tiley * 2 + wc;
  #pragma unroll
  for (int mb = 0; mb < 4; ++mb) {
    #pragma unroll
    for (int j = 0; j < 4; ++j) {
      float lg[4], ct[4];
      #pragma unroll
      for (int nb = 0; nb < 4; ++nb) {
        lg[nb] = acc[mb][nb][j] * WINV + bv[nb];
        const ushort4 v = c8[nb * 2 + (mb >> 1)][mb & 1];
        ct[nb] = bf2f(j == 0 ? v.x : j == 1 ? v.y : j == 2 ? v.z : v.w);
      }
      float tmax = fmaxf(fmaxf(lg[0], lg[1]), fmaxf(lg[2], lg[3]));
      #pragma unroll
      for (int d = 1; d < 16; d <<= 1) tmax = fmaxf(tmax, __shfl_xor(tmax, d));
      float le = 0.f, se = 0.f;
      #pragma unroll
      for (int nb = 0; nb < 4; ++nb) {
        const float e = __expf(lg[nb] - tmax);
        le += e; se += e * ct[nb];
      }
      #pragma unroll
      for (int d = 1; d < 16; d <<= 1) {
        le += __shfl_xor(le, d);
        se += __shfl_xor(se, d);
      }
      if (lcol == 0) {
        const int row = tilex * MT + wr * 64 + mb * 16 + quad * 4 + j;
        pm[chunk * NTOK + row] = tmax;
        pl[chunk * NTOK + row] = le;
        ps[chunk * NTOK + row] = se;
      }
    }
  }
}

// -------- merge strip partials -> scalar loss (last block finalizes) -------
__global__ __launch_bounds__(256) void k_merge(
    const int* __restrict__ counter, const float* __restrict__ tsq,
    const float* __restrict__ pm, const float* __restrict__ pl,
    const float* __restrict__ ps, float* __restrict__ lsum,
    int* __restrict__ done, float* __restrict__ out) {
  const int n = *counter;
  const int ga = blockIdx.x * 256 + threadIdx.x;
  float val = 0.f;
  if (ga < n) {
    float M = -1e30f;
    for (int j = 0; j < NCHK; ++j) M = fmaxf(M, pm[j * NTOK + ga]);
    float L = 0.f, S = 0.f;
    for (int j = 0; j < NCHK; ++j) {
      const float e = __expf(pm[j * NTOK + ga] - M);
      L += pl[j * NTOK + ga] * e;
      S += ps[j * NTOK + ga] * e;
    }
    val = (tsq[ga] + CTC + S / L) * (LOSSW / (float)H);
  }
  #pragma unroll
  for (int d = 1; d < 64; d <<= 1) val += __shfl_xor(val, d);
  __shared__ float wsum[4];
  if ((threadIdx.x & 63) == 0) wsum[threadIdx.x >> 6] = val;
  __syncthreads();
  if (threadIdx.x == 0) {
    atomicAdd(lsum, wsum[0] + wsum[1] + wsum[2] + wsum[3]);
    __threadfence();
    const int tk = atomicAdd(done, 1);
    if (tk == (int)gridDim.x - 1) {
      __threadfence();
      out[0] = atomicAdd(lsum, 0.0f);   // atomic read-back = final sum
    }
  }
}

// ---------------------------------------------------------------------------
extern "C" void kernel_launch(void* const* d_in, const int* in_sizes, int n_in,
                              void* d_out, int out_size, void* d_ws, size_t ws_size,
                              hipStream_t stream) {
  const float* hs   = (const float*)d_in[0];
  const int*   ids  = (const int*)d_in[1];
  const float* tg   = (const float*)d_in[2];
  const float* cb   = (const float*)d_in[3];
  const float* W    = (const float*)d_in[4];
  const float* bias = (const float*)d_in[5];

  char* ws = (char*)d_ws;
  constexpr size_t OFF_CSQ  = 0;                       // f32[8192] (zeroed)
  constexpr size_t OFF_TSQ  = 32768;                   // f32[8192] (zeroed)
  constexpr size_t OFF_CNT  = 65536;                   // int (zeroed)
  constexpr size_t OFF_DONE = 65540;                   // int (zeroed)
  constexpr size_t OFF_LSUM = 65544;                   // f32 (zeroed)
  constexpr size_t ZERO_BYTES = 65548;
  constexpr size_t OFF_LIST = 65664;                   // int[8192]
  constexpr size_t OFF_AHS  = 98432;                   // fp8 slab 8 MiB
  constexpr size_t OFF_ATG  = OFF_AHS + (size_t)NTOK * H;
  constexpr size_t OFF_WTB  = OFF_ATG + (size_t)NTOK * H;
  constexpr size_t OFF_CBB  = OFF_WTB + (size_t)CBN * H;
  constexpr size_t OFF_PM   = OFF_CBB + (size_t)CBN * H;
  constexpr size_t OFF_PL   = OFF_PM + (size_t)NCHK * NTOK * 4;
  constexpr size_t OFF_PS   = OFF_PL + (size_t)NCHK * NTOK * 4;
  constexpr size_t OFF_CTB  = OFF_PS + (size_t)NCHK * NTOK * 4;  // bf16 128 MiB

  float*          csq  = (float*)(ws + OFF_CSQ);
  float*          tsq  = (float*)(ws + OFF_TSQ);
  int*            cnt  = (int*)(ws + OFF_CNT);
  int*            done = (int*)(ws + OFF_DONE);
  float*          lsum = (float*)(ws + OFF_LSUM);
  int*            list = (int*)(ws + OFF_LIST);
  unsigned char*  Ahs  = (unsigned char*)(ws + OFF_AHS);
  unsigned char*  Atg  = (unsigned char*)(ws + OFF_ATG);
  unsigned char*  Wtb  = (unsigned char*)(ws + OFF_WTB);
  unsigned char*  Cbb  = (unsigned char*)(ws + OFF_CBB);
  float*          pm   = (float*)(ws + OFF_PM);
  float*          pl   = (float*)(ws + OFF_PL);
  float*          ps   = (float*)(ws + OFF_PS);
  unsigned short* ctB  = (unsigned short*)(ws + OFF_CTB);

  hipMemsetAsync(ws, 0, ZERO_BYTES, stream);

  k_prep1<<<1312, 256, 0, stream>>>(ids, cb, W, list, cnt, csq, Wtb, Cbb);
  k_prep_a<<<256, 256, 0, stream>>>(hs, tg, list, cnt, Ahs, Atg, tsq);
  k_cross<<<dim3(64, 64), 256, 0, stream>>>(Atg, Cbb, csq, cnt, ctB);
  k_logit<<<dim3(64, 64), 256, 0, stream>>>(Ahs, Wtb, bias, ctB, cnt, pm, pl, ps);
  k_merge<<<NTOK / 256, 256, 0, stream>>>(cnt, tsq, pm, pl, ps, lsum, done,
                                          (float*)d_out);
}

// Round 6
// 313.846 us; speedup vs baseline: 1.4781x; 1.0143x over previous
//
#include <hip/hip_runtime.h>
#include <hip/hip_bf16.h>

// ---------------------------------------------------------------------------
// TokenDiscrepancyLoss: loss = 0.1 * sum_{mask} [ (||t||^2 + sum_c p_c (||c||^2 - 2 t.c)) / H ]
// with p = softmax(hs @ W + b) over C=8192.
//
// R6: single k_dual kernel runs BOTH fp8 GEMMs sequentially per (128x128)
// tile: phase 1 (tg x codebook) -> ct held in 32 bf16-pair VGPRs (no memory
// round trip), phase 2 (hs x W) reusing the same 32 KB LDS double-buffer,
// one fused softmax epilogue. Phase boundary prefetched (no vmcnt(0) between
// phases). fp8 e4m3 k-major slabs; contiguous global->LDS DMA; vmcnt(4).
// Dispatches: memset, prep1, prep_a, k_dual, k_merge (5 total).
// ---------------------------------------------------------------------------

#define H        1024
#define CBN      8192
#define NTOK     8192
#define MT       128
#define NTILE    128
#define BK       64
#define NKC      16               // H / BK
#define NCHK     128              // partial strips (one per 64-col wave tile)
#define LOSSW    0.1f
#define CTC      1024.0f          // centering for bf16 ct registers
#define WSCALE   16.0f            // W pre-scale (pow2) for fp8 range
#define WINV     0.0625f
#define SLAB     131072           // bytes per 128-row panel: 16kc*8g*128r*8B

typedef __attribute__((ext_vector_type(4))) float f32x4;

__device__ __forceinline__ unsigned short f2bf(float f) {
  union { float f; unsigned u; } x; x.f = f;
  return (unsigned short)((x.u + 0x7FFFu + ((x.u >> 16) & 1u)) >> 16); // RNE
}
__device__ __forceinline__ float bf2f(unsigned short u) {
  union { unsigned u; float f; } x; x.u = (unsigned)u << 16;
  return x.f;
}

// ---- fp32 -> fp8 e4m3fn (OCP) ----
__device__ unsigned char f2fp8_sw(float f) {
  float a = fabsf(f);
  unsigned s = f < 0.f ? 0x80u : 0u;
  if (!(a < 448.f)) return (unsigned char)(s | 0x7Eu);
  if (a < 0.0009765625f) return (unsigned char)s;
  int e; float m = frexpf(a, &e);
  int te = e - 1;
  if (te < -6) {
    int q = (int)rintf(a * 512.f); if (q > 7) q = 7;
    return (unsigned char)(s | q);
  }
  int q = (int)rintf((2.f * m - 1.f) * 8.f);
  int E = te + 7, M = q;
  if (q == 8) { E += 1; M = 0; }
  if (E > 15) return (unsigned char)(s | 0x7Eu);
  return (unsigned char)(s | (E << 3) | M);
}
__device__ __forceinline__ unsigned pack4(float a, float b, float c, float d) {
#if __has_builtin(__builtin_amdgcn_cvt_pk_fp8_f32)
  int r = __builtin_amdgcn_cvt_pk_fp8_f32(a, b, 0, false);
  r     = __builtin_amdgcn_cvt_pk_fp8_f32(c, d, r, true);
  return (unsigned)r;
#else
  return (unsigned)f2fp8_sw(a) | ((unsigned)f2fp8_sw(b) << 8) |
         ((unsigned)f2fp8_sw(c) << 16) | ((unsigned)f2fp8_sw(d) << 24);
#endif
}

// async global->LDS DMA, 16B/lane; LDS dest = wave-uniform base + lane*16
__device__ __forceinline__ void load_lds16(const void* g, void* l) {
  __builtin_amdgcn_global_load_lds((const __attribute__((address_space(1))) void*)g,
                                   (__attribute__((address_space(3))) void*)l,
                                   16, 0, 0);
}
__device__ __forceinline__ void wait_vm4() { asm volatile("s_waitcnt vmcnt(4)" ::: "memory"); }
__device__ __forceinline__ void wait_vm0() { asm volatile("s_waitcnt vmcnt(0)" ::: "memory"); }
__device__ __forceinline__ void barrier_raw() { asm volatile("s_barrier" ::: "memory"); }

// XCD-aware tile mapping
__device__ __forceinline__ void tile_map(int* tilex, int* tiley) {
  const int flat = blockIdx.y * 64 + blockIdx.x;
  const int xcd = flat & 7, loc = flat >> 3;
  *tiley = xcd * 8 + (loc & 7);
  *tilex = loc >> 3;
}

// ---------------- prep1: compact (32 blk) + W (1024 blk) + cb (256 blk) ----
__global__ __launch_bounds__(256) void k_prep1(
    const int* __restrict__ ids, const float* __restrict__ cb,
    const float* __restrict__ W,
    int* __restrict__ list, int* __restrict__ counter,
    float* __restrict__ csq,
    unsigned char* __restrict__ Wtb, unsigned char* __restrict__ Cbb) {
  __shared__ __align__(16) unsigned char tile[8192];
  const int b = blockIdx.x, t = threadIdx.x;
  if (b < 32) {
    int f = 0;
    #pragma unroll
    for (int j = 0; j < 16; ++j) f |= ids[2 * (t * 16 + j) + 1];
    int anyodd = __syncthreads_or(f);
    int i = b * 256 + t;
    int v = anyodd ? ids[i] : ids[2 * i];
    bool act = (v == 1);
    unsigned long long mask = __ballot(act);
    int lane = t & 63;
    int base = 0;
    if (lane == 0) base = atomicAdd(counter, __popcll(mask));
    base = __shfl(base, 0);
    if (act) list[base + __popcll(mask & ((1ull << lane) - 1ull))] = i;
  } else if (b < 1056) {
    // W [H][C] fp32 -> fp8 slab [tiley][kc][g][c][8], scaled x16
    const int q = b - 32, tiley = q >> 4, kc = q & 15;
    const int c = t & 127, gh = t >> 7;
    unsigned char* dst = Wtb + (size_t)tiley * SLAB + (size_t)kc * 8192;
    #pragma unroll
    for (int gi = 0; gi < 4; ++gi) {
      const int g = gh * 4 + gi;
      const float* wp = W + (size_t)(kc * 64 + g * 8) * CBN + tiley * 128 + c;
      float v[8];
      #pragma unroll
      for (int j = 0; j < 8; ++j) v[j] = wp[(size_t)j * CBN] * WSCALE;
      uint2 pk;
      pk.x = pack4(v[0], v[1], v[2], v[3]);
      pk.y = pack4(v[4], v[5], v[6], v[7]);
      *(uint2*)(dst + g * 1024 + c * 8) = pk;
    }
  } else {
    // codebook [C][H] fp32 -> fp8 slab + csq partials
    const int q = b - 1056, tiley = q >> 2, kcg = q & 3;
    const int r = t >> 1, h = t & 1;
    const int c = tiley * 128 + r;
    float ss = 0.f;
    for (int kk = 0; kk < 4; ++kk) {
      const int kc = kcg * 4 + kk;
      const float4* s4 = (const float4*)(cb + (size_t)c * H + kc * 64 + h * 32);
      #pragma unroll
      for (int i = 0; i < 4; ++i) {
        float4 va = s4[2 * i], vb = s4[2 * i + 1];
        ss += va.x * va.x + va.y * va.y + va.z * va.z + va.w * va.w;
        ss += vb.x * vb.x + vb.y * vb.y + vb.z * vb.z + vb.w * vb.w;
        uint2 pk;
        pk.x = pack4(va.x, va.y, va.z, va.w);
        pk.y = pack4(vb.x, vb.y, vb.z, vb.w);
        *(uint2*)&tile[(h * 4 + i) * 1024 + r * 8] = pk;
      }
      __syncthreads();
      const uint4* tp = (const uint4*)tile;
      uint4 x0 = tp[t * 2], x1 = tp[t * 2 + 1];
      unsigned char* dst = Cbb + (size_t)tiley * SLAB + (size_t)kc * 8192 + t * 32;
      *(uint4*)dst = x0; *(uint4*)(dst + 16) = x1;
      __syncthreads();
    }
    ss += __shfl_xor(ss, 1);
    if (h == 0) atomicAdd(&csq[c], ss);
  }
}

// ------- gather active tokens -> fp8 slabs (hs, tg) + fp32 ||t||^2 ---------
__global__ __launch_bounds__(256) void k_prep_a(
    const float* __restrict__ hs, const float* __restrict__ tg,
    const int* __restrict__ list, const int* __restrict__ counter,
    unsigned char* __restrict__ Ahs, unsigned char* __restrict__ Atg,
    float* __restrict__ tsq) {
  const int n = *counter;
  const int n_pad = (n + MT - 1) & ~(MT - 1);
  const int tilex = blockIdx.x >> 2, kcg = blockIdx.x & 3;
  if (tilex * MT >= n_pad) return;
  __shared__ int stok[128];
  __shared__ __align__(16) unsigned char tile[8192];
  const int t = threadIdx.x, r = t >> 1, h = t & 1;
  if (t < 128) {
    int ga = tilex * MT + t;
    stok[t] = list[(ga < n) ? ga : 0];
  }
  __syncthreads();
  const size_t srow = (size_t)stok[r] * H;
  float ss = 0.f;
  for (int kk = 0; kk < 4; ++kk) {
    const int kc = kcg * 4 + kk;
    {
      const float4* s4 = (const float4*)(hs + srow + kc * 64 + h * 32);
      #pragma unroll
      for (int i = 0; i < 4; ++i) {
        float4 va = s4[2 * i], vb = s4[2 * i + 1];
        uint2 pk;
        pk.x = pack4(va.x, va.y, va.z, va.w);
        pk.y = pack4(vb.x, vb.y, vb.z, vb.w);
        *(uint2*)&tile[(h * 4 + i) * 1024 + r * 8] = pk;
      }
      __syncthreads();
      const uint4* tp = (const uint4*)tile;
      uint4 x0 = tp[t * 2], x1 = tp[t * 2 + 1];
      unsigned char* dst = Ahs + (size_t)tilex * SLAB + (size_t)kc * 8192 + t * 32;
      *(uint4*)dst = x0; *(uint4*)(dst + 16) = x1;
      __syncthreads();
    }
    {
      const float4* s4 = (const float4*)(tg + srow + kc * 64 + h * 32);
      #pragma unroll
      for (int i = 0; i < 4; ++i) {
        float4 va = s4[2 * i], vb = s4[2 * i + 1];
        ss += va.x * va.x + va.y * va.y + va.z * va.z + va.w * va.w;
        ss += vb.x * vb.x + vb.y * vb.y + vb.z * vb.z + vb.w * vb.w;
        uint2 pk;
        pk.x = pack4(va.x, va.y, va.z, va.w);
        pk.y = pack4(vb.x, vb.y, vb.z, vb.w);
        *(uint2*)&tile[(h * 4 + i) * 1024 + r * 8] = pk;
      }
      __syncthreads();
      const uint4* tp = (const uint4*)tile;
      uint4 x0 = tp[t * 2], x1 = tp[t * 2 + 1];
      unsigned char* dst = Atg + (size_t)tilex * SLAB + (size_t)kc * 8192 + t * 32;
      *(uint4*)dst = x0; *(uint4*)(dst + 16) = x1;
      __syncthreads();
    }
  }
  ss += __shfl_xor(ss, 1);
  if (h == 0) atomicAdd(&tsq[tilex * MT + r], ss);
}

// per-wave DMA batch: 4 contiguous 1 KB wave-loads (2 A granule-rows + 2 B)
#define ISSUE(Aslab, Bslab, kc, pb)                                        \
  do {                                                                     \
    const unsigned char* ap_ = (Aslab) + Aoff + (size_t)(kc) * 8192 + lane * 16; \
    const unsigned char* bp_ = (Bslab) + Boff + (size_t)(kc) * 8192 + lane * 16; \
    load_lds16(ap_ + w * 1024,       &sA[pb][w * 1024]);                   \
    load_lds16(ap_ + (w + 4) * 1024, &sA[pb][(w + 4) * 1024]);             \
    load_lds16(bp_ + w * 1024,       &sB[pb][w * 1024]);                   \
    load_lds16(bp_ + (w + 4) * 1024, &sB[pb][(w + 4) * 1024]);             \
  } while (0)

// one kc compute step: 2 ks x 16 fp8 MFMA from buffer `cur`
#define COMPUTE_KC(cur)                                                    \
  do {                                                                     \
    _Pragma("unroll")                                                      \
    for (int ks = 0; ks < 2; ++ks) {                                       \
      const int gb = (ks * 4 + quad) * 1024;                               \
      long aF[4], bF[4];                                                   \
      _Pragma("unroll")                                                    \
      for (int mb = 0; mb < 4; ++mb)                                       \
        aF[mb] = *(const long*)&sA[cur][gb + (wr * 64 + mb * 16 + lcol) * 8]; \
      _Pragma("unroll")                                                    \
      for (int nb = 0; nb < 4; ++nb)                                       \
        bF[nb] = *(const long*)&sB[cur][gb + (wc * 64 + nb * 16 + lcol) * 8]; \
      _Pragma("unroll")                                                    \
      for (int mb = 0; mb < 4; ++mb)                                       \
        _Pragma("unroll")                                                  \
        for (int nb = 0; nb < 4; ++nb)                                     \
          acc[mb][nb] = __builtin_amdgcn_mfma_f32_16x16x32_fp8_fp8(        \
              aF[mb], bF[nb], acc[mb][nb], 0, 0, 0);                       \
    }                                                                      \
  } while (0)

// ---------- dual-phase GEMM: cross (ct -> regs) then logits+softmax --------
__global__ __launch_bounds__(256, 3) void k_dual(
    const unsigned char* __restrict__ Atg, const unsigned char* __restrict__ Cbb,
    const unsigned char* __restrict__ Ahs, const unsigned char* __restrict__ Wtb,
    const float* __restrict__ csq, const float* __restrict__ bias,
    const int* __restrict__ counter,
    float* __restrict__ pm, float* __restrict__ pl, float* __restrict__ ps) {
  const int n = *counter;
  int tilex, tiley;
  tile_map(&tilex, &tiley);
  if (tilex * MT >= n) return;

  __shared__ __align__(16) unsigned char sA[2][8192];
  __shared__ __align__(16) unsigned char sB[2][8192];

  const int t = threadIdx.x;
  const int w = t >> 6, lane = t & 63;
  const int wr = w >> 1, wc = w & 1;
  const int quad = lane >> 4, lcol = lane & 15;
  const size_t Aoff = (size_t)tilex * SLAB;
  const size_t Boff = (size_t)tiley * SLAB;

  f32x4 acc[4][4];
  #pragma unroll
  for (int mb = 0; mb < 4; ++mb)
    #pragma unroll
    for (int nb = 0; nb < 4; ++nb) acc[mb][nb] = (f32x4){0.f, 0.f, 0.f, 0.f};

  // ---------------- phase 1: ct = csq - 2 * (tg x codebook^T) --------------
  ISSUE(Atg, Cbb, 0, 0);
  #pragma unroll
  for (int kc = 0; kc < NKC; ++kc) {
    const int cur = kc & 1;
    if (kc + 1 < NKC) ISSUE(Atg, Cbb, kc + 1, cur ^ 1);
    else              ISSUE(Ahs, Wtb, 0, 0);      // phase-boundary prefetch
    wait_vm4();
    barrier_raw();
    COMPUTE_KC(cur);
    barrier_raw();
  }

  // pack ct into bf16-pair registers (no memory round trip)
  unsigned ctp[4][4][2];
  {
    float cqc[4];
    #pragma unroll
    for (int nb = 0; nb < 4; ++nb)
      cqc[nb] = csq[tiley * NTILE + wc * 64 + nb * 16 + lcol] - CTC;
    #pragma unroll
    for (int mb = 0; mb < 4; ++mb)
      #pragma unroll
      for (int nb = 0; nb < 4; ++nb) {
        const float v0 = cqc[nb] - 2.f * acc[mb][nb][0];
        const float v1 = cqc[nb] - 2.f * acc[mb][nb][1];
        const float v2 = cqc[nb] - 2.f * acc[mb][nb][2];
        const float v3 = cqc[nb] - 2.f * acc[mb][nb][3];
        ctp[mb][nb][0] = (unsigned)f2bf(v0) | ((unsigned)f2bf(v1) << 16);
        ctp[mb][nb][1] = (unsigned)f2bf(v2) | ((unsigned)f2bf(v3) << 16);
        acc[mb][nb] = (f32x4){0.f, 0.f, 0.f, 0.f};
      }
  }

  // ---------------- phase 2: logits = hs x W^T (scaled) --------------------
  #pragma unroll
  for (int kc = 0; kc < NKC; ++kc) {
    const int cur = kc & 1;
    if (kc + 1 < NKC) { ISSUE(Ahs, Wtb, kc + 1, cur ^ 1); wait_vm4(); }
    else              { wait_vm0(); }
    barrier_raw();
    COMPUTE_KC(cur);
    barrier_raw();
  }

  // ---------------- fused softmax epilogue per 64-col strip ----------------
  float bv[4];
  #pragma unroll
  for (int nb = 0; nb < 4; ++nb)
    bv[nb] = bias[tiley * NTILE + wc * 64 + nb * 16 + lcol];

  const int chunk = tiley * 2 + wc;
  #pragma unroll
  for (int mb = 0; mb < 4; ++mb) {
    #pragma unroll
    for (int j = 0; j < 4; ++j) {
      float lg[4], ct[4];
      #pragma unroll
      for (int nb = 0; nb < 4; ++nb) {
        lg[nb] = acc[mb][nb][j] * WINV + bv[nb];
        ct[nb] = bf2f((unsigned short)((ctp[mb][nb][j >> 1] >> ((j & 1) * 16)) & 0xFFFFu));
      }
      float tmax = fmaxf(fmaxf(lg[0], lg[1]), fmaxf(lg[2], lg[3]));
      #pragma unroll
      for (int d = 1; d < 16; d <<= 1) tmax = fmaxf(tmax, __shfl_xor(tmax, d));
      float le = 0.f, se = 0.f;
      #pragma unroll
      for (int nb = 0; nb < 4; ++nb) {
        const float e = __expf(lg[nb] - tmax);
        le += e; se += e * ct[nb];
      }
      #pragma unroll
      for (int d = 1; d < 16; d <<= 1) {
        le += __shfl_xor(le, d);
        se += __shfl_xor(se, d);
      }
      if (lcol == 0) {
        const int row = tilex * MT + wr * 64 + mb * 16 + quad * 4 + j;
        pm[chunk * NTOK + row] = tmax;
        pl[chunk * NTOK + row] = le;
        ps[chunk * NTOK + row] = se;
      }
    }
  }
}

// -------- merge strip partials -> scalar loss (last block finalizes) -------
__global__ __launch_bounds__(256) void k_merge(
    const int* __restrict__ counter, const float* __restrict__ tsq,
    const float* __restrict__ pm, const float* __restrict__ pl,
    const float* __restrict__ ps, float* __restrict__ lsum,
    int* __restrict__ done, float* __restrict__ out) {
  const int n = *counter;
  const int ga = blockIdx.x * 256 + threadIdx.x;
  float val = 0.f;
  if (ga < n) {
    float M = -1e30f;
    for (int j = 0; j < NCHK; ++j) M = fmaxf(M, pm[j * NTOK + ga]);
    float L = 0.f, S = 0.f;
    for (int j = 0; j < NCHK; ++j) {
      const float e = __expf(pm[j * NTOK + ga] - M);
      L += pl[j * NTOK + ga] * e;
      S += ps[j * NTOK + ga] * e;
    }
    val = (tsq[ga] + CTC + S / L) * (LOSSW / (float)H);
  }
  #pragma unroll
  for (int d = 1; d < 64; d <<= 1) val += __shfl_xor(val, d);
  __shared__ float wsum[4];
  if ((threadIdx.x & 63) == 0) wsum[threadIdx.x >> 6] = val;
  __syncthreads();
  if (threadIdx.x == 0) {
    atomicAdd(lsum, wsum[0] + wsum[1] + wsum[2] + wsum[3]);
    __threadfence();
    const int tk = atomicAdd(done, 1);
    if (tk == (int)gridDim.x - 1) {
      __threadfence();
      out[0] = atomicAdd(lsum, 0.0f);   // atomic read-back = final sum
    }
  }
}

// ---------------------------------------------------------------------------
extern "C" void kernel_launch(void* const* d_in, const int* in_sizes, int n_in,
                              void* d_out, int out_size, void* d_ws, size_t ws_size,
                              hipStream_t stream) {
  const float* hs   = (const float*)d_in[0];
  const int*   ids  = (const int*)d_in[1];
  const float* tg   = (const float*)d_in[2];
  const float* cb   = (const float*)d_in[3];
  const float* W    = (const float*)d_in[4];
  const float* bias = (const float*)d_in[5];

  char* ws = (char*)d_ws;
  constexpr size_t OFF_CSQ  = 0;                       // f32[8192] (zeroed)
  constexpr size_t OFF_TSQ  = 32768;                   // f32[8192] (zeroed)
  constexpr size_t OFF_CNT  = 65536;                   // int (zeroed)
  constexpr size_t OFF_DONE = 65540;                   // int (zeroed)
  constexpr size_t OFF_LSUM = 65544;                   // f32 (zeroed)
  constexpr size_t ZERO_BYTES = 65548;
  constexpr size_t OFF_LIST = 65664;                   // int[8192]
  constexpr size_t OFF_AHS  = 98432;                   // fp8 slab 8 MiB
  constexpr size_t OFF_ATG  = OFF_AHS + (size_t)NTOK * H;
  constexpr size_t OFF_WTB  = OFF_ATG + (size_t)NTOK * H;
  constexpr size_t OFF_CBB  = OFF_WTB + (size_t)CBN * H;
  constexpr size_t OFF_PM   = OFF_CBB + (size_t)CBN * H;
  constexpr size_t OFF_PL   = OFF_PM + (size_t)NCHK * NTOK * 4;
  constexpr size_t OFF_PS   = OFF_PL + (size_t)NCHK * NTOK * 4;

  float*          csq  = (float*)(ws + OFF_CSQ);
  float*          tsq  = (float*)(ws + OFF_TSQ);
  int*            cnt  = (int*)(ws + OFF_CNT);
  int*            done = (int*)(ws + OFF_DONE);
  float*          lsum = (float*)(ws + OFF_LSUM);
  int*            list = (int*)(ws + OFF_LIST);
  unsigned char*  Ahs  = (unsigned char*)(ws + OFF_AHS);
  unsigned char*  Atg  = (unsigned char*)(ws + OFF_ATG);
  unsigned char*  Wtb  = (unsigned char*)(ws + OFF_WTB);
  unsigned char*  Cbb  = (unsigned char*)(ws + OFF_CBB);
  float*          pm   = (float*)(ws + OFF_PM);
  float*          pl   = (float*)(ws + OFF_PL);
  float*          ps   = (float*)(ws + OFF_PS);

  hipMemsetAsync(ws, 0, ZERO_BYTES, stream);

  k_prep1<<<1312, 256, 0, stream>>>(ids, cb, W, list, cnt, csq, Wtb, Cbb);
  k_prep_a<<<256, 256, 0, stream>>>(hs, tg, list, cnt, Ahs, Atg, tsq);
  k_dual<<<dim3(64, 64), 256, 0, stream>>>(Atg, Cbb, Ahs, Wtb, csq, bias, cnt,
                                           pm, pl, ps);
  k_merge<<<NTOK / 256, 256, 0, stream>>>(cnt, tsq, pm, pl, ps, lsum, done,
                                          (float*)d_out);
}